// Round 8
// baseline (309.996 us; speedup 1.0000x reference)
//
#include <hip/hip_runtime.h>
#include <hip/hip_bf16.h>
#include <math.h>

// Problem constants (B=2, T=2048, C=2048, NH=16, NKV=4, D=128, HALF=64)
#define BB 2
#define TT 2048
#define CC 2048
#define NH 16
#define NKV 4
#define HD 128
#define HALF 64
#define MTOT (BB*TT)            // 4096
#define NQKV (CC + 2*NKV*HD)    // 3072 (fused q|k|v columns)

typedef unsigned short u16;
typedef __attribute__((ext_vector_type(8))) short bf16x8;
typedef __attribute__((ext_vector_type(4))) float f32x4;

// fp32 -> bf16 (round-to-nearest-even), bit-twiddle form
__device__ __forceinline__ u16 f2bf(float f) {
  unsigned u = __float_as_uint(f);
  unsigned r = (u + 0x7FFFu + ((u >> 16) & 1u)) >> 16;
  return (u16)r;
}
// fp32 -> bf16 via HW convert (RNE, identical results; fewer VALU ops)
__device__ __forceinline__ u16 f2bf_hw(float f) {
  __hip_bfloat16 h = __float2bfloat16(f);
  return *reinterpret_cast<const u16*>(&h);
}
__device__ __forceinline__ float bf2f(u16 v) {
  return __uint_as_float(((unsigned)v) << 16);
}

// async global->LDS, 16B per lane; lds base must be wave-uniform (HW adds lane*16)
__device__ __forceinline__ void gl_lds16(const void* g, void* l) {
  __builtin_amdgcn_global_load_lds(
      (const __attribute__((address_space(1))) unsigned int*)g,
      (__attribute__((address_space(3))) unsigned int*)l, 16, 0, 0);
}

// XCD-chunked block swizzle (T1): dispatched bid b runs logical tile
// (b%8)*cpx + b/8, so each XCD's round-robin share is a CONTIGUOUS tile
// range -> operand panels reused within one XCD's L2 instead of refetched
// by all 8. Bijective iff nwg % 8 == 0 (true: 192 and 256).
__device__ __forceinline__ int xcd_swz(int bid, int nwg) {
  return (bid & 7) * (nwg >> 3) + (bid >> 3);
}

// ---------------------------------------------------------------------------
// prep: fused x->bf16 convert (z=4) + 4 weight transposes (z=0..3).
// grid (64, 64, 5), block (32, 8).
// ---------------------------------------------------------------------------
__global__ __launch_bounds__(256) void prep(
    const float* __restrict__ x, const float* __restrict__ Wq,
    const float* __restrict__ Wk, const float* __restrict__ Wv,
    const float* __restrict__ Wo, u16* __restrict__ xb,
    u16* __restrict__ Wt, u16* __restrict__ Wot) {
  const int z = blockIdx.z;
  const int tx = threadIdx.x, ty = threadIdx.y;
  if (z == 4) {
    const int tid = ty * 32 + tx;
    const int i = (blockIdx.y * 64 + blockIdx.x) * 256 + tid;  // 8-elem group
    const float4* s4 = (const float4*)x;
    float4 a = s4[(size_t)i * 2], b = s4[(size_t)i * 2 + 1];
    bf16x8 o;
    o[0] = (short)f2bf(a.x); o[1] = (short)f2bf(a.y);
    o[2] = (short)f2bf(a.z); o[3] = (short)f2bf(a.w);
    o[4] = (short)f2bf(b.x); o[5] = (short)f2bf(b.y);
    o[6] = (short)f2bf(b.z); o[7] = (short)f2bf(b.w);
    ((bf16x8*)xb)[i] = o;
    return;
  }
  const float* W; u16* dst; int N; int row_off;
  if (z == 0)      { W = Wq; dst = Wt;  N = 2048; row_off = 0; }
  else if (z == 1) { W = Wk; dst = Wt;  N = 512;  row_off = 2048; }
  else if (z == 2) { W = Wv; dst = Wt;  N = 512;  row_off = 2560; }
  else             { W = Wo; dst = Wot; N = 2048; row_off = 0; }
  const int n0 = blockIdx.x * 32, k0 = blockIdx.y * 32;
  if (n0 >= N) return;
  __shared__ float tile[32][33];
#pragma unroll
  for (int i = 0; i < 4; ++i)
    tile[ty + 8 * i][tx] = W[(size_t)(k0 + ty + 8 * i) * N + n0 + tx];
  __syncthreads();
#pragma unroll
  for (int i = 0; i < 4; ++i)
    dst[(size_t)(row_off + n0 + ty + 8 * i) * CC + k0 + tx] =
        f2bf(tile[tx][ty + 8 * i]);
}

// ---------------------------------------------------------------------------
// 256x256 8-phase bf16 MFMA GEMM (m201-style template, plain HIP).
// Verified r2: conflicts ~0, swizzle byte^=((row&7)<<4) both sides.
// r7: + XCD-chunked block swizzle (FETCH_SIZE 78 MB vs 29 MB ideal = L2
// panel refetch across XCDs; chunking makes A-panel reuse XCD-local).
// ---------------------------------------------------------------------------
__global__ __launch_bounds__(512, 2) void gemm_8ph(
    const u16* __restrict__ A, const u16* __restrict__ Bt,
    const float* __restrict__ bias, float* __restrict__ C,
    int M, int N, int K, int out_bf16) {
  __shared__ u16 As[32768];   // 2 x (256x64) bf16 = 2 x 32 KB
  __shared__ u16 Bs[32768];
  const int tid = threadIdx.x;
  const int w = tid >> 6, lane = tid & 63;
  const int quad = lane >> 4, lo = lane & 15;
  const int wm = w >> 2, wn = w & 3;          // 2M x 4N wave grid
  const int nwg = gridDim.x * gridDim.y;
  const int swz = xcd_swz(blockIdx.y * gridDim.x + blockIdx.x, nwg);
  const int bm = (swz / gridDim.x) * 256, bn = (swz % gridDim.x) * 256;
  const int NT = K >> 6;                      // K-tiles of 64 (NT >= 2)

  const u16* agp[2][2]; const u16* bgp[2][2];
#pragma unroll
  for (int h = 0; h < 2; ++h)
#pragma unroll
    for (int j = 0; j < 2; ++j) {
      const unsigned X = (unsigned)h * 16384u +
                         (unsigned)((w * 2 + j) * 64 + lane) * 16u;
      const int row = (int)(X >> 7);
      const int ce = (int)(((X & 127u) ^ (((X >> 7) & 7u) << 4)) >> 1);
      agp[h][j] = A  + (size_t)(bm + row) * K + ce;
      bgp[h][j] = Bt + (size_t)(bn + row) * K + ce;
    }
  char* const lAs = (char*)As;
  char* const lBs = (char*)Bs;
  const int woff = w * 2048;

#define STGA(hh, bufp, kt) do { \
    gl_lds16(agp[hh][0] + (size_t)(kt) * 64, lAs + (bufp) * 32768 + (hh) * 16384 + woff); \
    gl_lds16(agp[hh][1] + (size_t)(kt) * 64, lAs + (bufp) * 32768 + (hh) * 16384 + woff + 1024); \
  } while (0)
#define STGB(hh, bufp, kt) do { \
    gl_lds16(bgp[hh][0] + (size_t)(kt) * 64, lBs + (bufp) * 32768 + (hh) * 16384 + woff); \
    gl_lds16(bgp[hh][1] + (size_t)(kt) * 64, lBs + (bufp) * 32768 + (hh) * 16384 + woff + 1024); \
  } while (0)

  const int sw  = (lo & 7) << 4;
  const int co0 = (quad * 16) ^ sw;
  const int co1 = (64 + quad * 16) ^ sw;
  const int aRB = (wm * 128 + lo) * 128;      // + qr*8192 + i*2048
  const int bRB = (wn * 64 + lo) * 128;       // + qc*4096 + j*2048

  f32x4 acc[8][4];
#pragma unroll
  for (int ri = 0; ri < 8; ++ri)
#pragma unroll
    for (int ci = 0; ci < 4; ++ci)
#pragma unroll
      for (int r = 0; r < 4; ++r) acc[ri][ci][r] = 0.f;

  STGA(0, 0, 0); STGA(1, 0, 0); STGB(0, 0, 0); STGB(1, 0, 0);
  STGB(0, 1, 1); STGB(1, 1, 1); STGA(0, 1, 1);
  asm volatile("s_waitcnt vmcnt(6)" ::: "memory");
  __builtin_amdgcn_s_barrier();

  for (int t = 0; t < NT; ++t) {
    const int pa = t & 1;
    const char* Ab = lAs + pa * 32768 + aRB;
    const char* Bb = lBs + pa * 32768 + bRB;
    bf16x8 a[4][2], b0[2][2], b1[2][2];

    // ---- phase 0: quadrant (qr=0, qc=0) --------------------------------
#pragma unroll
    for (int i = 0; i < 4; ++i) {
      a[i][0] = *(const bf16x8*)(Ab + i * 2048 + co0);
      a[i][1] = *(const bf16x8*)(Ab + i * 2048 + co1);
    }
#pragma unroll
    for (int j = 0; j < 2; ++j) {
      b0[j][0] = *(const bf16x8*)(Bb + j * 2048 + co0);
      b0[j][1] = *(const bf16x8*)(Bb + j * 2048 + co1);
    }
    if (t + 1 < NT) STGA(1, (t + 1) & 1, t + 1);
    __builtin_amdgcn_s_barrier();
    asm volatile("s_waitcnt lgkmcnt(0)");
    __builtin_amdgcn_s_setprio(1);
#pragma unroll
    for (int i = 0; i < 4; ++i)
#pragma unroll
      for (int j = 0; j < 2; ++j) {
        acc[i][j] = __builtin_amdgcn_mfma_f32_16x16x32_bf16(a[i][0], b0[j][0], acc[i][j], 0, 0, 0);
        acc[i][j] = __builtin_amdgcn_mfma_f32_16x16x32_bf16(a[i][1], b0[j][1], acc[i][j], 0, 0, 0);
      }
    __builtin_amdgcn_s_setprio(0);
    __builtin_amdgcn_s_barrier();

    // ---- phase 1: quadrant (qr=0, qc=1) --------------------------------
#pragma unroll
    for (int j = 0; j < 2; ++j) {
      b1[j][0] = *(const bf16x8*)(Bb + 4096 + j * 2048 + co0);
      b1[j][1] = *(const bf16x8*)(Bb + 4096 + j * 2048 + co1);
    }
    __builtin_amdgcn_s_barrier();
    asm volatile("s_waitcnt lgkmcnt(0)");
    __builtin_amdgcn_s_setprio(1);
#pragma unroll
    for (int i = 0; i < 4; ++i)
#pragma unroll
      for (int j = 0; j < 2; ++j) {
        acc[i][2 + j] = __builtin_amdgcn_mfma_f32_16x16x32_bf16(a[i][0], b1[j][0], acc[i][2 + j], 0, 0, 0);
        acc[i][2 + j] = __builtin_amdgcn_mfma_f32_16x16x32_bf16(a[i][1], b1[j][1], acc[i][2 + j], 0, 0, 0);
      }
    __builtin_amdgcn_s_setprio(0);
    __builtin_amdgcn_s_barrier();

    // ---- phase 2: quadrant (qr=1, qc=1) --------------------------------
#pragma unroll
    for (int i = 0; i < 4; ++i) {
      a[i][0] = *(const bf16x8*)(Ab + 8192 + i * 2048 + co0);
      a[i][1] = *(const bf16x8*)(Ab + 8192 + i * 2048 + co1);
    }
    if (t + 2 < NT) STGB(0, pa, t + 2);
    __builtin_amdgcn_s_barrier();
    asm volatile("s_waitcnt lgkmcnt(0)");
    __builtin_amdgcn_s_setprio(1);
#pragma unroll
    for (int i = 0; i < 4; ++i)
#pragma unroll
      for (int j = 0; j < 2; ++j) {
        acc[4 + i][2 + j] = __builtin_amdgcn_mfma_f32_16x16x32_bf16(a[i][0], b1[j][0], acc[4 + i][2 + j], 0, 0, 0);
        acc[4 + i][2 + j] = __builtin_amdgcn_mfma_f32_16x16x32_bf16(a[i][1], b1[j][1], acc[4 + i][2 + j], 0, 0, 0);
      }
    __builtin_amdgcn_s_setprio(0);
    __builtin_amdgcn_s_barrier();

    // ---- phase 3: quadrant (qr=1, qc=0); counted wait ------------------
    if (t + 2 < NT) { STGB(1, pa, t + 2); STGA(0, pa, t + 2); }
    if (t + 2 < NT)      asm volatile("s_waitcnt vmcnt(6)" ::: "memory");
    else if (t + 1 < NT) asm volatile("s_waitcnt vmcnt(0)" ::: "memory");
    __builtin_amdgcn_s_barrier();
    asm volatile("s_waitcnt lgkmcnt(0)");
    __builtin_amdgcn_s_setprio(1);
#pragma unroll
    for (int i = 0; i < 4; ++i)
#pragma unroll
      for (int j = 0; j < 2; ++j) {
        acc[4 + i][j] = __builtin_amdgcn_mfma_f32_16x16x32_bf16(a[i][0], b0[j][0], acc[4 + i][j], 0, 0, 0);
        acc[4 + i][j] = __builtin_amdgcn_mfma_f32_16x16x32_bf16(a[i][1], b0[j][1], acc[4 + i][j], 0, 0, 0);
      }
    __builtin_amdgcn_s_setprio(0);
    __builtin_amdgcn_s_barrier();
  }
#undef STGA
#undef STGB

  const int rbase = bm + wm * 128;
  const int cbase = bn + wn * 64;
#pragma unroll
  for (int ri = 0; ri < 8; ++ri)
#pragma unroll
    for (int ci = 0; ci < 4; ++ci) {
      const int col = cbase + ci * 16 + lo;
      const float bv = bias ? bias[col] : 0.f;
#pragma unroll
      for (int r = 0; r < 4; ++r) {
        const int row = rbase + ri * 16 + quad * 4 + r;
        const float v = acc[ri][ci][r] + bv;
        if (out_bf16) ((u16*)C)[(size_t)row * N + col] = f2bf(v);
        else          C[(size_t)row * N + col] = v;
      }
    }
}

// ---------------------------------------------------------------------------
// 256x128 2-phase bf16 MFMA GEMM — grid-fill variant for the out-proj
// (N=2048 -> 16x16 = 256 blocks = 1/CU). Verified r4. r7: + XCD swizzle.
// ---------------------------------------------------------------------------
__global__ __launch_bounds__(512, 2) void gemm_n128(
    const u16* __restrict__ A, const u16* __restrict__ Bt,
    const float* __restrict__ bias, float* __restrict__ C,
    int M, int N, int K, int out_bf16) {
  __shared__ u16 As[32768];   // 2 x (256x64) bf16
  __shared__ u16 Bs[16384];   // 2 x (128x64) bf16
  const int tid = threadIdx.x;
  const int w = tid >> 6, lane = tid & 63;
  const int quad = lane >> 4, lo = lane & 15;
  const int wm = w >> 1, wn = w & 1;          // 4M x 2N wave grid
  const int nwg = gridDim.x * gridDim.y;
  const int swz = xcd_swz(blockIdx.y * gridDim.x + blockIdx.x, nwg);
  const int bm = (swz / gridDim.x) * 256, bn = (swz % gridDim.x) * 128;
  const int NT = K >> 6;                      // K-tiles of 64 (NT >= 3)

  const u16* agp[2][2];
#pragma unroll
  for (int h = 0; h < 2; ++h)
#pragma unroll
    for (int j = 0; j < 2; ++j) {
      const unsigned X = (unsigned)h * 16384u +
                         (unsigned)((w * 2 + j) * 64 + lane) * 16u;
      const int row = (int)(X >> 7);
      const int ce = (int)(((X & 127u) ^ (((X >> 7) & 7u) << 4)) >> 1);
      agp[h][j] = A + (size_t)(bm + row) * K + ce;
    }
  const u16* bgp[2];
#pragma unroll
  for (int j = 0; j < 2; ++j) {
    const unsigned X = (unsigned)((w * 2 + j) * 64 + lane) * 16u;
    const int row = (int)(X >> 7);
    const int ce = (int)(((X & 127u) ^ (((X >> 7) & 7u) << 4)) >> 1);
    bgp[j] = Bt + (size_t)(bn + row) * K + ce;
  }
  char* const lAs = (char*)As;
  char* const lBs = (char*)Bs;
  const int woff = w * 2048;

#define STGA_(hh, bufp, kt) do { \
    gl_lds16(agp[hh][0] + (size_t)(kt) * 64, lAs + (bufp) * 32768 + (hh) * 16384 + woff); \
    gl_lds16(agp[hh][1] + (size_t)(kt) * 64, lAs + (bufp) * 32768 + (hh) * 16384 + woff + 1024); \
  } while (0)
#define STGB_(bufp, kt) do { \
    gl_lds16(bgp[0] + (size_t)(kt) * 64, lBs + (bufp) * 16384 + woff); \
    gl_lds16(bgp[1] + (size_t)(kt) * 64, lBs + (bufp) * 16384 + woff + 1024); \
  } while (0)

  const int sw  = (lo & 7) << 4;
  const int co0 = (quad * 16) ^ sw;
  const int co1 = (64 + quad * 16) ^ sw;
  const int aRB = (wm * 64 + lo) * 128;       // + i*2048
  const int bRB = (wn * 64 + lo) * 128;       // + ci*2048

  f32x4 acc[4][4];
#pragma unroll
  for (int i = 0; i < 4; ++i)
#pragma unroll
    for (int ci = 0; ci < 4; ++ci)
#pragma unroll
      for (int r = 0; r < 4; ++r) acc[i][ci][r] = 0.f;

  STGA_(0, 0, 0); STGA_(1, 0, 0); STGB_(0, 0);
  STGB_(1, 1); STGA_(0, 1, 1);
  asm volatile("s_waitcnt vmcnt(4)" ::: "memory");
  __builtin_amdgcn_s_barrier();

  for (int t = 0; t < NT; ++t) {
    const int pa = t & 1;
    const char* Ab = lAs + pa * 32768 + aRB;
    const char* Bb = lBs + pa * 16384 + bRB;
    bf16x8 a[4][2], b[4][2];
#pragma unroll
    for (int i = 0; i < 4; ++i) {
      a[i][0] = *(const bf16x8*)(Ab + i * 2048 + co0);
      a[i][1] = *(const bf16x8*)(Ab + i * 2048 + co1);
    }
#pragma unroll
    for (int ci = 0; ci < 4; ++ci) {
      b[ci][0] = *(const bf16x8*)(Bb + ci * 2048 + co0);
      b[ci][1] = *(const bf16x8*)(Bb + ci * 2048 + co1);
    }
    if (t + 1 < NT) STGA_(1, (t + 1) & 1, t + 1);
    asm volatile("s_waitcnt lgkmcnt(0)");   // own reads done BEFORE barrier
    __builtin_amdgcn_s_barrier();           // -> all waves' reads of buf pa done
    __builtin_amdgcn_s_setprio(1);
#pragma unroll
    for (int i = 0; i < 4; ++i)
#pragma unroll
      for (int ci = 0; ci < 2; ++ci) {
        acc[i][ci] = __builtin_amdgcn_mfma_f32_16x16x32_bf16(a[i][0], b[ci][0], acc[i][ci], 0, 0, 0);
        acc[i][ci] = __builtin_amdgcn_mfma_f32_16x16x32_bf16(a[i][1], b[ci][1], acc[i][ci], 0, 0, 0);
      }
    __builtin_amdgcn_s_setprio(0);
    if (t + 2 < NT) { STGB_(pa, t + 2); STGA_(0, pa, t + 2); }
    if (t + 2 < NT)      asm volatile("s_waitcnt vmcnt(4)" ::: "memory");
    else if (t + 1 < NT) asm volatile("s_waitcnt vmcnt(0)" ::: "memory");
    __builtin_amdgcn_s_setprio(1);
#pragma unroll
    for (int i = 0; i < 4; ++i)
#pragma unroll
      for (int ci = 2; ci < 4; ++ci) {
        acc[i][ci] = __builtin_amdgcn_mfma_f32_16x16x32_bf16(a[i][0], b[ci][0], acc[i][ci], 0, 0, 0);
        acc[i][ci] = __builtin_amdgcn_mfma_f32_16x16x32_bf16(a[i][1], b[ci][1], acc[i][ci], 0, 0, 0);
      }
    __builtin_amdgcn_s_setprio(0);
    __builtin_amdgcn_s_barrier();           // next iter reads need all DMAs in
  }
#undef STGA_
#undef STGB_

  const int rbase = bm + wm * 64;
  const int cbase = bn + wn * 64;
#pragma unroll
  for (int i = 0; i < 4; ++i)
#pragma unroll
    for (int ci = 0; ci < 4; ++ci) {
      const int col = cbase + ci * 16 + lo;
      const float bv = bias ? bias[col] : 0.f;
#pragma unroll
      for (int r = 0; r < 4; ++r) {
        const int row = rbase + i * 16 + quad * 4 + r;
        const float v = acc[i][ci][r] + bv;
        if (out_bf16) ((u16*)C)[(size_t)row * N + col] = f2bf(v);
        else          C[(size_t)row * N + col] = v;
      }
    }
}

// ---------------------------------------------------------------------------
// FUSED qkv_post + v_transpose. grid (B*T, 6), block 256.
//   y in [0,5): RMSNorm + RoPE, one wave per (b,t,head). r7: VECTORIZED —
//     lane l loads/stores u32 (elements 2l, 2l+1); the RoPE pair
//     (x1[j], x2[j]) for j = 2*(l&31), +1 is gathered with two __shfl:
//     x1 pair lives at lane j/2 (<32), x2 pair at lane 32+j/2.
//     Reduce total unchanged (each element counted once).
//   y == 5: v-transpose (unchanged, verified r7).
// ---------------------------------------------------------------------------
__global__ __launch_bounds__(256) void qkv_post(
    const u16* __restrict__ qkv_lin, const float* __restrict__ cosp,
    const float* __restrict__ sinp, u16* __restrict__ q, u16* __restrict__ k,
    u16* __restrict__ vt) {
  __shared__ u16 tile[32][33];
  if (blockIdx.y == 5) {
    const int bx = blockIdx.x;
    if (bx >= 2048) return;
    const int t0 = (bx & 63) * 32, d0 = ((bx >> 6) & 3) * 32;
    const int p = bx >> 8;              // b*NKV + kv
    const int b = p >> 2, kv = p & 3;
    const int tx = threadIdx.x & 31, ty = threadIdx.x >> 5;
#pragma unroll
    for (int i = 0; i < 4; ++i)
      tile[ty + 8 * i][tx] =
          qkv_lin[(size_t)(b * TT + t0 + ty + 8 * i) * NQKV + CC + NKV * HD + kv * HD + d0 + tx];
    __syncthreads();
    const int tperm = ((tx >> 2) & 3) * 8 + (tx & 3) + 4 * ((tx >> 4) & 1);
#pragma unroll
    for (int i = 0; i < 4; ++i)
      vt[((size_t)p * HD + d0 + ty + 8 * i) * TT + t0 + tperm] = tile[tx][ty + 8 * i];
    return;
  }
  const int bt = blockIdx.x;
  const int hh = blockIdx.y * 4 + (threadIdx.x >> 6);   // 0..19
  const int lane = threadIdx.x & 63;
  const int lam = lane & 31;
  const int t = bt & (TT - 1), b = bt >> 11;
  const int col = (hh < NH) ? hh * HD : CC + (hh - NH) * HD;
  const u16* src = qkv_lin + (size_t)bt * NQKV + col;
  const unsigned wv = *(const unsigned*)(src + 2 * lane);   // elems 2l, 2l+1
  const float e0 = bf2f((u16)(wv & 0xFFFFu)), e1 = bf2f((u16)(wv >> 16));
  float ss = e0 * e0 + e1 * e1;
#pragma unroll
  for (int mm = 1; mm < 64; mm <<= 1) ss += __shfl_xor(ss, mm, 64);
  const float rms = rsqrtf(ss * (1.f / 128.f) + 1.1920929e-7f);
  // gather RoPE pair for elements j = 2*lam, 2*lam+1
  const unsigned w1 = (unsigned)__shfl((int)wv, lam, 64);        // x1 pair
  const unsigned w2 = (unsigned)__shfl((int)wv, lam + 32, 64);   // x2 pair
  const float x1a = bf2f((u16)(w1 & 0xFFFFu)), x1b = bf2f((u16)(w1 >> 16));
  const float x2a = bf2f((u16)(w2 & 0xFFFFu)), x2b = bf2f((u16)(w2 >> 16));
  const float2 cs = *(const float2*)(cosp + t * HALF + 2 * lam);
  const float2 sn = *(const float2*)(sinp + t * HALF + 2 * lam);
  float oa, ob;
  if (lane < 32) {   // o1[j] = x1*rms*c - x2*rms*s
    oa = x1a * rms * cs.x - x2a * rms * sn.x;
    ob = x1b * rms * cs.y - x2b * rms * sn.y;
  } else {           // o2[j] = x1*rms*s + x2*rms*c
    oa = x1a * rms * sn.x + x2a * rms * cs.x;
    ob = x1b * rms * sn.y + x2b * rms * cs.y;
  }
  const unsigned ow = (unsigned)f2bf(oa) | ((unsigned)f2bf(ob) << 16);
  u16* dst = (hh < NH)
      ? q + (((size_t)(b * NH + hh)) * TT + t) * HD
      : k + (((size_t)(b * NKV + (hh - NH))) * TT + t) * HD;
  *(unsigned*)(dst + 2 * lane) = ow;   // elems 2l, 2l+1 (o1|o2 layout matches)
}

// ---------------------------------------------------------------------------
// S^T softmax + A-fragment pack, all in registers (v5-verified math).
// ---------------------------------------------------------------------------
__device__ __forceinline__ void softmax_pack(
    const f32x4* sacc, float& l_lane, bf16x8* ap, int rowq, int t0,
    bool diag, int quad) {
  const float cc = 0.12751744050808612f;   // log2(e)/sqrt(128)
  float e[4][4];
  if (diag) {
#pragma unroll
    for (int ct = 0; ct < 4; ++ct)
#pragma unroll
      for (int r = 0; r < 4; ++r) {
        float v = __builtin_amdgcn_exp2f(sacc[ct][r] * cc);
        if (t0 + ct * 16 + quad * 4 + r > rowq) v = 0.f;
        l_lane += v; e[ct][r] = v;
      }
  } else {
#pragma unroll
    for (int ct = 0; ct < 4; ++ct)
#pragma unroll
      for (int r = 0; r < 4; ++r) {
        float v = __builtin_amdgcn_exp2f(sacc[ct][r] * cc);
        l_lane += v; e[ct][r] = v;
      }
  }
#pragma unroll
  for (int k2 = 0; k2 < 2; ++k2) {
    bf16x8 ch;
#pragma unroll
    for (int j = 0; j < 8; ++j)
      ch[j] = (short)f2bf_hw(e[k2 * 2 + (j >> 2)][j & 3]);
    ap[k2] = ch;
  }
}

// ---------------------------------------------------------------------------
// MFMA flash attention v7 (r5/r7-verified, ~72.7 µs): rb-split, 8 waves,
// 64 KB double-buffered LDS -> 2 blocks/CU (cross-block overlap is the
// latency-hiding mechanism — r6's 96 KB variant at 1 block/CU was 1.8x worse).
// ---------------------------------------------------------------------------
__global__ __launch_bounds__(512, 4) void attn_mfma(
    const u16* __restrict__ Qb, const u16* __restrict__ Kb,
    const u16* __restrict__ Vt, u16* __restrict__ Y) {
  __shared__ u16 Ks[2][8192];   // 16 sets (ct*4+kc) x 512, dbuf
  __shared__ u16 Vs[2][8192];   // 16 sets (dt*2+k2) x 512, dbuf

  const int qt = blockIdx.x;    // pair (qt, 31-qt)
  const int bh = blockIdx.y;
  const int b = bh >> 4, h = bh & 15, kvh = h >> 2;
  const int tid = threadIdx.x;
  const int wave = tid >> 6, lane = tid & 63;
  const int wg = wave >> 2, wv = wave & 3;   // wg: 0 = tile A, 1 = tile B
  const int quad = lane >> 4, lo = lane & 15;

  const int rows = (wg == 0) ? qt * 64 : (31 - qt) * 64;
  const u16* Qg = Qb + (size_t)(b * NH + h) * TT * HD;
  const u16* Kg = Kb + (size_t)(b * NKV + kvh) * TT * HD;
  const u16* Vg = Vt + (size_t)(b * NKV + kvh) * HD * TT;

  // Q fragments, used as MFMA B-operand (n=lo -> q-row, k=quad*8+j)
  bf16x8 aq[4];
#pragma unroll
  for (int kc = 0; kc < 4; ++kc)
    aq[kc] = *(const bf16x8*)(Qg + (size_t)(rows + wv * 16 + lo) * HD + kc * 32 + quad * 8);

  // staging: wave stages K sets {wave*2, wave*2+1} and V sets {wave*2, wave*2+1}
  const u16* kgp[2]; const u16* vgp[2];
  u16* klp[2][2]; u16* vlp[2][2];
#pragma unroll
  for (int c = 0; c < 2; ++c) {
    const int s = wave * 2 + c;          // 0..15
    const int ct = s >> 2, kq = s & 3;
    kgp[c] = Kg + (size_t)(ct * 16 + lo) * HD + kq * 32 + quad * 8;
    const int dt = s >> 1, k2 = s & 1;
    vgp[c] = Vg + (size_t)(dt * 16 + lo) * TT + k2 * 32 + quad * 8;
    klp[0][c] = &Ks[0][s * 512]; klp[1][c] = &Ks[1][s * 512];
    vlp[0][c] = &Vs[0][s * 512]; vlp[1][c] = &Vs[1][s * 512];
  }

  f32x4 oacc[8];
#pragma unroll
  for (int dt = 0; dt < 8; ++dt)
#pragma unroll
    for (int r = 0; r < 4; ++r) oacc[dt][r] = 0.f;
  float l_lane = 0.f;

  const int ntiles = 32 - qt;
  const int rowq = rows + wv * 16 + lo;   // this lane's q-row

  // prologue: stage tile 0 -> buf 0
#pragma unroll
  for (int c = 0; c < 2; ++c) {
    gl_lds16(kgp[c], klp[0][c]); kgp[c] += 64 * HD;
    gl_lds16(vgp[c], vlp[0][c]); vgp[c] += 64;
  }

  for (int nt = 0; nt < ntiles; ++nt) {
    const int par = nt & 1;
    __syncthreads();  // tile nt landed (vmcnt drained); buf[par^1] readers done
    if (nt + 1 < ntiles) {
#pragma unroll
      for (int c = 0; c < 2; ++c) {
        gl_lds16(kgp[c], klp[par ^ 1][c]); kgp[c] += 64 * HD;
        gl_lds16(vgp[c], vlp[par ^ 1][c]); vgp[c] += 64;
      }
    }
    const bool act = (wg == 1) || (nt <= qt);
    if (act) {
      const u16* ksb = Ks[par];
      const u16* vsb = Vs[par];
      const int t0 = nt * 64;

      // S^T = K Q^T: D row (quad*4+r) = kv, col (lo) = q-row
      f32x4 sacc[4];
#pragma unroll
      for (int ct = 0; ct < 4; ++ct)
#pragma unroll
        for (int r = 0; r < 4; ++r) sacc[ct][r] = 0.f;
      __builtin_amdgcn_s_setprio(1);
#pragma unroll
      for (int ct = 0; ct < 4; ++ct)
#pragma unroll
        for (int kc = 0; kc < 4; ++kc) {
          bf16x8 bk = *(const bf16x8*)&ksb[(ct * 4 + kc) * 512 + lane * 8];
          sacc[ct] = __builtin_amdgcn_mfma_f32_16x16x32_bf16(bk, aq[kc], sacc[ct], 0, 0, 0);
        }
      __builtin_amdgcn_s_setprio(0);

      // softmax + register P pack
      bf16x8 ap[2];
      softmax_pack(sacc, l_lane, ap, rowq, t0, t0 + 63 > rows + wv * 16, quad);

      // O += P @ V  (V already in permuted kv order matching the pack)
      __builtin_amdgcn_s_setprio(1);
#pragma unroll
      for (int dt = 0; dt < 8; ++dt)
#pragma unroll
        for (int k2 = 0; k2 < 2; ++k2) {
          bf16x8 bv = *(const bf16x8*)&vsb[(dt * 2 + k2) * 512 + lane * 8];
          oacc[dt] = __builtin_amdgcn_mfma_f32_16x16x32_bf16(ap[k2], bv, oacc[dt], 0, 0, 0);
        }
      __builtin_amdgcn_s_setprio(0);
    }
  }

  // epilogue: l for q-row `lo` -> reduce over quad lanes; fetch per-output-row
  float l = l_lane;
  l += __shfl_xor(l, 16, 64);
  l += __shfl_xor(l, 32, 64);
  l = 1.f / l;                       // valid at lane lo for row lo (all quads)
  float linv[4];
#pragma unroll
  for (int r = 0; r < 4; ++r)
    linv[r] = __shfl(l, quad * 4 + r, 64);   // row quad*4+r lives at lane quad*4+r
  const size_t row0 = (size_t)b * TT + rows + wv * 16 + quad * 4;
#pragma unroll
  for (int dt = 0; dt < 8; ++dt)
#pragma unroll
    for (int r = 0; r < 4; ++r)
      Y[(row0 + r) * CC + h * HD + dt * 16 + lo] = f2bf(oacc[dt][r] * linv[r]);
}

// ---------------------------------------------------------------------------
// kernel_launch. ws layout (bytes):
//   [0,16M):   xb (bf16 x)            -> later qb_buf (bf16 q, B,H,T,D)
//   [16M,28M): Wt (bf16 qkv^T)        -> later kb (4M) + vt (8M)
//   [28M,52M): qkv_lin bf16 (M x 3072)-> first 16M later y (bf16, M x C)
//   [52M,60M): Wot (bf16 Wo^T)
// ---------------------------------------------------------------------------
extern "C" void kernel_launch(void* const* d_in, const int* in_sizes, int n_in,
                              void* d_out, int out_size, void* d_ws, size_t ws_size,
                              hipStream_t stream) {
  (void)in_sizes; (void)n_in; (void)out_size; (void)ws_size;
  const float* x    = (const float*)d_in[0];
  const float* cosp = (const float*)d_in[1];
  const float* sinp = (const float*)d_in[2];
  const float* Wq   = (const float*)d_in[3];
  const float* Wk   = (const float*)d_in[4];
  const float* Wv   = (const float*)d_in[5];
  const float* Wo   = (const float*)d_in[6];
  const float* bo   = (const float*)d_in[7];
  float* out = (float*)d_out;
  char* ws = (char*)d_ws;

  const size_t MB = 1024 * 1024;
  u16* xb      = (u16*)(ws);
  u16* Wt      = (u16*)(ws + 16 * MB);
  u16* qkv_lin = (u16*)(ws + 28 * MB);
  u16* Wot     = (u16*)(ws + 52 * MB);
  u16* qb_buf  = (u16*)(ws);             // alias xb (dead after GEMM1)
  u16* kb      = (u16*)(ws + 16 * MB);   // alias Wt
  u16* vt      = (u16*)(ws + 20 * MB);   // alias Wt+4M
  u16* y       = (u16*)(ws + 28 * MB);   // alias qkv_lin head (dead after post)

  // 1. fused convert + weight transposes
  prep<<<dim3(64, 64, 5), dim3(32, 8), 0, stream>>>(x, Wq, Wk, Wv, Wo, xb, Wt, Wot);

  // 2. fused QKV GEMM (M=4096, N=3072, K=2048), bf16 out
  gemm_8ph<<<dim3(NQKV / 256, MTOT / 256), 512, 0, stream>>>(
      xb, Wt, nullptr, (float*)qkv_lin, MTOT, NQKV, CC, 1);

  // 3. fused RMSNorm+RoPE (y<5, vectorized) + V-transpose (y==5)
  qkv_post<<<dim3(MTOT, 6), 256, 0, stream>>>(qkv_lin, cosp, sinp, qb_buf, kb, vt);

  // 4. MFMA flash attention v7 -> y bf16 (M x C)
  attn_mfma<<<dim3(16, BB * NH), 512, 0, stream>>>(qb_buf, kb, vt, y);

  // 5. out-proj GEMM + bias (fp32 out) — 256x128 tiles: 256 blocks = 1/CU
  gemm_n128<<<dim3(CC / 128, MTOT / 256), 512, 0, stream>>>(
      y, Wot, bo, out, MTOT, CC, CC, 0);
}

// Round 9
// 306.607 us; speedup vs baseline: 1.0111x; 1.0111x over previous
//
#include <hip/hip_runtime.h>
#include <hip/hip_bf16.h>
#include <math.h>

// Problem constants (B=2, T=2048, C=2048, NH=16, NKV=4, D=128, HALF=64)
#define BB 2
#define TT 2048
#define CC 2048
#define NH 16
#define NKV 4
#define HD 128
#define HALF 64
#define MTOT (BB*TT)            // 4096
#define NQKV (CC + 2*NKV*HD)    // 3072 (fused q|k|v columns)

typedef unsigned short u16;
typedef __attribute__((ext_vector_type(8))) short bf16x8;
typedef __attribute__((ext_vector_type(4))) float f32x4;

// fp32 -> bf16 (round-to-nearest-even), bit-twiddle form
__device__ __forceinline__ u16 f2bf(float f) {
  unsigned u = __float_as_uint(f);
  unsigned r = (u + 0x7FFFu + ((u >> 16) & 1u)) >> 16;
  return (u16)r;
}
// fp32 -> bf16 via HW convert (RNE, identical results; fewer VALU ops)
__device__ __forceinline__ u16 f2bf_hw(float f) {
  __hip_bfloat16 h = __float2bfloat16(f);
  return *reinterpret_cast<const u16*>(&h);
}
__device__ __forceinline__ float bf2f(u16 v) {
  return __uint_as_float(((unsigned)v) << 16);
}

// async global->LDS, 16B per lane; lds base must be wave-uniform (HW adds lane*16)
__device__ __forceinline__ void gl_lds16(const void* g, void* l) {
  __builtin_amdgcn_global_load_lds(
      (const __attribute__((address_space(1))) unsigned int*)g,
      (__attribute__((address_space(3))) unsigned int*)l, 16, 0, 0);
}

// XCD-chunked block swizzle (T1): dispatched bid b runs logical tile
// (b%8)*cpx + b/8, so each XCD's round-robin share is a CONTIGUOUS tile
// range -> operand panels reused within one XCD's L2 instead of refetched
// by all 8. Bijective iff nwg % 8 == 0 (true: 192 and 256).
__device__ __forceinline__ int xcd_swz(int bid, int nwg) {
  return (bid & 7) * (nwg >> 3) + (bid >> 3);
}

// ---------------------------------------------------------------------------
// prep: fused x->bf16 convert (z=4) + 4 weight transposes (z=0..3).
// grid (64, 64, 5), block (32, 8).
// ---------------------------------------------------------------------------
__global__ __launch_bounds__(256) void prep(
    const float* __restrict__ x, const float* __restrict__ Wq,
    const float* __restrict__ Wk, const float* __restrict__ Wv,
    const float* __restrict__ Wo, u16* __restrict__ xb,
    u16* __restrict__ Wt, u16* __restrict__ Wot) {
  const int z = blockIdx.z;
  const int tx = threadIdx.x, ty = threadIdx.y;
  if (z == 4) {
    const int tid = ty * 32 + tx;
    const int i = (blockIdx.y * 64 + blockIdx.x) * 256 + tid;  // 8-elem group
    const float4* s4 = (const float4*)x;
    float4 a = s4[(size_t)i * 2], b = s4[(size_t)i * 2 + 1];
    bf16x8 o;
    o[0] = (short)f2bf(a.x); o[1] = (short)f2bf(a.y);
    o[2] = (short)f2bf(a.z); o[3] = (short)f2bf(a.w);
    o[4] = (short)f2bf(b.x); o[5] = (short)f2bf(b.y);
    o[6] = (short)f2bf(b.z); o[7] = (short)f2bf(b.w);
    ((bf16x8*)xb)[i] = o;
    return;
  }
  const float* W; u16* dst; int N; int row_off;
  if (z == 0)      { W = Wq; dst = Wt;  N = 2048; row_off = 0; }
  else if (z == 1) { W = Wk; dst = Wt;  N = 512;  row_off = 2048; }
  else if (z == 2) { W = Wv; dst = Wt;  N = 512;  row_off = 2560; }
  else             { W = Wo; dst = Wot; N = 2048; row_off = 0; }
  const int n0 = blockIdx.x * 32, k0 = blockIdx.y * 32;
  if (n0 >= N) return;
  __shared__ float tile[32][33];
#pragma unroll
  for (int i = 0; i < 4; ++i)
    tile[ty + 8 * i][tx] = W[(size_t)(k0 + ty + 8 * i) * N + n0 + tx];
  __syncthreads();
#pragma unroll
  for (int i = 0; i < 4; ++i)
    dst[(size_t)(row_off + n0 + ty + 8 * i) * CC + k0 + tx] =
        f2bf(tile[tx][ty + 8 * i]);
}

// ---------------------------------------------------------------------------
// 256x256 8-phase bf16 MFMA GEMM (m201-style template, plain HIP).
// Verified r2: conflicts ~0, swizzle byte^=((row&7)<<4) both sides.
// r7: + XCD-chunked block swizzle.
// ---------------------------------------------------------------------------
__global__ __launch_bounds__(512, 2) void gemm_8ph(
    const u16* __restrict__ A, const u16* __restrict__ Bt,
    const float* __restrict__ bias, float* __restrict__ C,
    int M, int N, int K, int out_bf16) {
  __shared__ u16 As[32768];   // 2 x (256x64) bf16 = 2 x 32 KB
  __shared__ u16 Bs[32768];
  const int tid = threadIdx.x;
  const int w = tid >> 6, lane = tid & 63;
  const int quad = lane >> 4, lo = lane & 15;
  const int wm = w >> 2, wn = w & 3;          // 2M x 4N wave grid
  const int nwg = gridDim.x * gridDim.y;
  const int swz = xcd_swz(blockIdx.y * gridDim.x + blockIdx.x, nwg);
  const int bm = (swz / gridDim.x) * 256, bn = (swz % gridDim.x) * 256;
  const int NT = K >> 6;                      // K-tiles of 64 (NT >= 2)

  const u16* agp[2][2]; const u16* bgp[2][2];
#pragma unroll
  for (int h = 0; h < 2; ++h)
#pragma unroll
    for (int j = 0; j < 2; ++j) {
      const unsigned X = (unsigned)h * 16384u +
                         (unsigned)((w * 2 + j) * 64 + lane) * 16u;
      const int row = (int)(X >> 7);
      const int ce = (int)(((X & 127u) ^ (((X >> 7) & 7u) << 4)) >> 1);
      agp[h][j] = A  + (size_t)(bm + row) * K + ce;
      bgp[h][j] = Bt + (size_t)(bn + row) * K + ce;
    }
  char* const lAs = (char*)As;
  char* const lBs = (char*)Bs;
  const int woff = w * 2048;

#define STGA(hh, bufp, kt) do { \
    gl_lds16(agp[hh][0] + (size_t)(kt) * 64, lAs + (bufp) * 32768 + (hh) * 16384 + woff); \
    gl_lds16(agp[hh][1] + (size_t)(kt) * 64, lAs + (bufp) * 32768 + (hh) * 16384 + woff + 1024); \
  } while (0)
#define STGB(hh, bufp, kt) do { \
    gl_lds16(bgp[hh][0] + (size_t)(kt) * 64, lBs + (bufp) * 32768 + (hh) * 16384 + woff); \
    gl_lds16(bgp[hh][1] + (size_t)(kt) * 64, lBs + (bufp) * 32768 + (hh) * 16384 + woff + 1024); \
  } while (0)

  const int sw  = (lo & 7) << 4;
  const int co0 = (quad * 16) ^ sw;
  const int co1 = (64 + quad * 16) ^ sw;
  const int aRB = (wm * 128 + lo) * 128;      // + qr*8192 + i*2048
  const int bRB = (wn * 64 + lo) * 128;       // + qc*4096 + j*2048

  f32x4 acc[8][4];
#pragma unroll
  for (int ri = 0; ri < 8; ++ri)
#pragma unroll
    for (int ci = 0; ci < 4; ++ci)
#pragma unroll
      for (int r = 0; r < 4; ++r) acc[ri][ci][r] = 0.f;

  STGA(0, 0, 0); STGA(1, 0, 0); STGB(0, 0, 0); STGB(1, 0, 0);
  STGB(0, 1, 1); STGB(1, 1, 1); STGA(0, 1, 1);
  asm volatile("s_waitcnt vmcnt(6)" ::: "memory");
  __builtin_amdgcn_s_barrier();

  for (int t = 0; t < NT; ++t) {
    const int pa = t & 1;
    const char* Ab = lAs + pa * 32768 + aRB;
    const char* Bb = lBs + pa * 32768 + bRB;
    bf16x8 a[4][2], b0[2][2], b1[2][2];

    // ---- phase 0: quadrant (qr=0, qc=0) --------------------------------
#pragma unroll
    for (int i = 0; i < 4; ++i) {
      a[i][0] = *(const bf16x8*)(Ab + i * 2048 + co0);
      a[i][1] = *(const bf16x8*)(Ab + i * 2048 + co1);
    }
#pragma unroll
    for (int j = 0; j < 2; ++j) {
      b0[j][0] = *(const bf16x8*)(Bb + j * 2048 + co0);
      b0[j][1] = *(const bf16x8*)(Bb + j * 2048 + co1);
    }
    if (t + 1 < NT) STGA(1, (t + 1) & 1, t + 1);
    __builtin_amdgcn_s_barrier();
    asm volatile("s_waitcnt lgkmcnt(0)");
    __builtin_amdgcn_s_setprio(1);
#pragma unroll
    for (int i = 0; i < 4; ++i)
#pragma unroll
      for (int j = 0; j < 2; ++j) {
        acc[i][j] = __builtin_amdgcn_mfma_f32_16x16x32_bf16(a[i][0], b0[j][0], acc[i][j], 0, 0, 0);
        acc[i][j] = __builtin_amdgcn_mfma_f32_16x16x32_bf16(a[i][1], b0[j][1], acc[i][j], 0, 0, 0);
      }
    __builtin_amdgcn_s_setprio(0);
    __builtin_amdgcn_s_barrier();

    // ---- phase 1: quadrant (qr=0, qc=1) --------------------------------
#pragma unroll
    for (int j = 0; j < 2; ++j) {
      b1[j][0] = *(const bf16x8*)(Bb + 4096 + j * 2048 + co0);
      b1[j][1] = *(const bf16x8*)(Bb + 4096 + j * 2048 + co1);
    }
    __builtin_amdgcn_s_barrier();
    asm volatile("s_waitcnt lgkmcnt(0)");
    __builtin_amdgcn_s_setprio(1);
#pragma unroll
    for (int i = 0; i < 4; ++i)
#pragma unroll
      for (int j = 0; j < 2; ++j) {
        acc[i][2 + j] = __builtin_amdgcn_mfma_f32_16x16x32_bf16(a[i][0], b1[j][0], acc[i][2 + j], 0, 0, 0);
        acc[i][2 + j] = __builtin_amdgcn_mfma_f32_16x16x32_bf16(a[i][1], b1[j][1], acc[i][2 + j], 0, 0, 0);
      }
    __builtin_amdgcn_s_setprio(0);
    __builtin_amdgcn_s_barrier();

    // ---- phase 2: quadrant (qr=1, qc=1) --------------------------------
#pragma unroll
    for (int i = 0; i < 4; ++i) {
      a[i][0] = *(const bf16x8*)(Ab + 8192 + i * 2048 + co0);
      a[i][1] = *(const bf16x8*)(Ab + 8192 + i * 2048 + co1);
    }
    if (t + 2 < NT) STGB(0, pa, t + 2);
    __builtin_amdgcn_s_barrier();
    asm volatile("s_waitcnt lgkmcnt(0)");
    __builtin_amdgcn_s_setprio(1);
#pragma unroll
    for (int i = 0; i < 4; ++i)
#pragma unroll
      for (int j = 0; j < 2; ++j) {
        acc[4 + i][2 + j] = __builtin_amdgcn_mfma_f32_16x16x32_bf16(a[i][0], b1[j][0], acc[4 + i][2 + j], 0, 0, 0);
        acc[4 + i][2 + j] = __builtin_amdgcn_mfma_f32_16x16x32_bf16(a[i][1], b1[j][1], acc[4 + i][2 + j], 0, 0, 0);
      }
    __builtin_amdgcn_s_setprio(0);
    __builtin_amdgcn_s_barrier();

    // ---- phase 3: quadrant (qr=1, qc=0); counted wait ------------------
    if (t + 2 < NT) { STGB(1, pa, t + 2); STGA(0, pa, t + 2); }
    if (t + 2 < NT)      asm volatile("s_waitcnt vmcnt(6)" ::: "memory");
    else if (t + 1 < NT) asm volatile("s_waitcnt vmcnt(0)" ::: "memory");
    __builtin_amdgcn_s_barrier();
    asm volatile("s_waitcnt lgkmcnt(0)");
    __builtin_amdgcn_s_setprio(1);
#pragma unroll
    for (int i = 0; i < 4; ++i)
#pragma unroll
      for (int j = 0; j < 2; ++j) {
        acc[4 + i][j] = __builtin_amdgcn_mfma_f32_16x16x32_bf16(a[i][0], b0[j][0], acc[4 + i][j], 0, 0, 0);
        acc[4 + i][j] = __builtin_amdgcn_mfma_f32_16x16x32_bf16(a[i][1], b0[j][1], acc[4 + i][j], 0, 0, 0);
      }
    __builtin_amdgcn_s_setprio(0);
    __builtin_amdgcn_s_barrier();
  }
#undef STGA
#undef STGB

  const int rbase = bm + wm * 128;
  const int cbase = bn + wn * 64;
#pragma unroll
  for (int ri = 0; ri < 8; ++ri)
#pragma unroll
    for (int ci = 0; ci < 4; ++ci) {
      const int col = cbase + ci * 16 + lo;
      const float bv = bias ? bias[col] : 0.f;
#pragma unroll
      for (int r = 0; r < 4; ++r) {
        const int row = rbase + ri * 16 + quad * 4 + r;
        const float v = acc[ri][ci][r] + bv;
        if (out_bf16) ((u16*)C)[(size_t)row * N + col] = f2bf(v);
        else          C[(size_t)row * N + col] = v;
      }
    }
}

// ---------------------------------------------------------------------------
// 256x128 2-phase bf16 MFMA GEMM — grid-fill variant for the out-proj
// (N=2048 -> 16x16 = 256 blocks = 1/CU). Verified r4. r7: + XCD swizzle.
// ---------------------------------------------------------------------------
__global__ __launch_bounds__(512, 2) void gemm_n128(
    const u16* __restrict__ A, const u16* __restrict__ Bt,
    const float* __restrict__ bias, float* __restrict__ C,
    int M, int N, int K, int out_bf16) {
  __shared__ u16 As[32768];   // 2 x (256x64) bf16
  __shared__ u16 Bs[16384];   // 2 x (128x64) bf16
  const int tid = threadIdx.x;
  const int w = tid >> 6, lane = tid & 63;
  const int quad = lane >> 4, lo = lane & 15;
  const int wm = w >> 1, wn = w & 1;          // 4M x 2N wave grid
  const int nwg = gridDim.x * gridDim.y;
  const int swz = xcd_swz(blockIdx.y * gridDim.x + blockIdx.x, nwg);
  const int bm = (swz / gridDim.x) * 256, bn = (swz % gridDim.x) * 128;
  const int NT = K >> 6;                      // K-tiles of 64 (NT >= 3)

  const u16* agp[2][2];
#pragma unroll
  for (int h = 0; h < 2; ++h)
#pragma unroll
    for (int j = 0; j < 2; ++j) {
      const unsigned X = (unsigned)h * 16384u +
                         (unsigned)((w * 2 + j) * 64 + lane) * 16u;
      const int row = (int)(X >> 7);
      const int ce = (int)(((X & 127u) ^ (((X >> 7) & 7u) << 4)) >> 1);
      agp[h][j] = A + (size_t)(bm + row) * K + ce;
    }
  const u16* bgp[2];
#pragma unroll
  for (int j = 0; j < 2; ++j) {
    const unsigned X = (unsigned)((w * 2 + j) * 64 + lane) * 16u;
    const int row = (int)(X >> 7);
    const int ce = (int)(((X & 127u) ^ (((X >> 7) & 7u) << 4)) >> 1);
    bgp[j] = Bt + (size_t)(bn + row) * K + ce;
  }
  char* const lAs = (char*)As;
  char* const lBs = (char*)Bs;
  const int woff = w * 2048;

#define STGA_(hh, bufp, kt) do { \
    gl_lds16(agp[hh][0] + (size_t)(kt) * 64, lAs + (bufp) * 32768 + (hh) * 16384 + woff); \
    gl_lds16(agp[hh][1] + (size_t)(kt) * 64, lAs + (bufp) * 32768 + (hh) * 16384 + woff + 1024); \
  } while (0)
#define STGB_(bufp, kt) do { \
    gl_lds16(bgp[0] + (size_t)(kt) * 64, lBs + (bufp) * 16384 + woff); \
    gl_lds16(bgp[1] + (size_t)(kt) * 64, lBs + (bufp) * 16384 + woff + 1024); \
  } while (0)

  const int sw  = (lo & 7) << 4;
  const int co0 = (quad * 16) ^ sw;
  const int co1 = (64 + quad * 16) ^ sw;
  const int aRB = (wm * 64 + lo) * 128;       // + i*2048
  const int bRB = (wn * 64 + lo) * 128;       // + ci*2048

  f32x4 acc[4][4];
#pragma unroll
  for (int i = 0; i < 4; ++i)
#pragma unroll
    for (int ci = 0; ci < 4; ++ci)
#pragma unroll
      for (int r = 0; r < 4; ++r) acc[i][ci][r] = 0.f;

  STGA_(0, 0, 0); STGA_(1, 0, 0); STGB_(0, 0);
  STGB_(1, 1); STGA_(0, 1, 1);
  asm volatile("s_waitcnt vmcnt(4)" ::: "memory");
  __builtin_amdgcn_s_barrier();

  for (int t = 0; t < NT; ++t) {
    const int pa = t & 1;
    const char* Ab = lAs + pa * 32768 + aRB;
    const char* Bb = lBs + pa * 16384 + bRB;
    bf16x8 a[4][2], b[4][2];
#pragma unroll
    for (int i = 0; i < 4; ++i) {
      a[i][0] = *(const bf16x8*)(Ab + i * 2048 + co0);
      a[i][1] = *(const bf16x8*)(Ab + i * 2048 + co1);
    }
#pragma unroll
    for (int ci = 0; ci < 4; ++ci) {
      b[ci][0] = *(const bf16x8*)(Bb + ci * 2048 + co0);
      b[ci][1] = *(const bf16x8*)(Bb + ci * 2048 + co1);
    }
    if (t + 1 < NT) STGA_(1, (t + 1) & 1, t + 1);
    asm volatile("s_waitcnt lgkmcnt(0)");   // own reads done BEFORE barrier
    __builtin_amdgcn_s_barrier();           // -> all waves' reads of buf pa done
    __builtin_amdgcn_s_setprio(1);
#pragma unroll
    for (int i = 0; i < 4; ++i)
#pragma unroll
      for (int ci = 0; ci < 2; ++ci) {
        acc[i][ci] = __builtin_amdgcn_mfma_f32_16x16x32_bf16(a[i][0], b[ci][0], acc[i][ci], 0, 0, 0);
        acc[i][ci] = __builtin_amdgcn_mfma_f32_16x16x32_bf16(a[i][1], b[ci][1], acc[i][ci], 0, 0, 0);
      }
    __builtin_amdgcn_s_setprio(0);
    if (t + 2 < NT) { STGB_(pa, t + 2); STGA_(0, pa, t + 2); }
    if (t + 2 < NT)      asm volatile("s_waitcnt vmcnt(4)" ::: "memory");
    else if (t + 1 < NT) asm volatile("s_waitcnt vmcnt(0)" ::: "memory");
    __builtin_amdgcn_s_setprio(1);
#pragma unroll
    for (int i = 0; i < 4; ++i)
#pragma unroll
      for (int ci = 2; ci < 4; ++ci) {
        acc[i][ci] = __builtin_amdgcn_mfma_f32_16x16x32_bf16(a[i][0], b[ci][0], acc[i][ci], 0, 0, 0);
        acc[i][ci] = __builtin_amdgcn_mfma_f32_16x16x32_bf16(a[i][1], b[ci][1], acc[i][ci], 0, 0, 0);
      }
    __builtin_amdgcn_s_setprio(0);
    __builtin_amdgcn_s_barrier();           // next iter reads need all DMAs in
  }
#undef STGA_
#undef STGB_

  const int rbase = bm + wm * 64;
  const int cbase = bn + wn * 64;
#pragma unroll
  for (int i = 0; i < 4; ++i)
#pragma unroll
    for (int ci = 0; ci < 4; ++ci) {
      const int col = cbase + ci * 16 + lo;
      const float bv = bias ? bias[col] : 0.f;
#pragma unroll
      for (int r = 0; r < 4; ++r) {
        const int row = rbase + i * 16 + quad * 4 + r;
        const float v = acc[i][ci][r] + bv;
        if (out_bf16) ((u16*)C)[(size_t)row * N + col] = f2bf(v);
        else          C[(size_t)row * N + col] = v;
      }
    }
}

// ---------------------------------------------------------------------------
// FUSED qkv_post + v_transpose. grid (B*T, 6), block 256.
//   y in [0,5): RMSNorm + RoPE, vectorized u32 loads/stores (verified r8).
//   y == 5: v-transpose (verified r7).
// ---------------------------------------------------------------------------
__global__ __launch_bounds__(256) void qkv_post(
    const u16* __restrict__ qkv_lin, const float* __restrict__ cosp,
    const float* __restrict__ sinp, u16* __restrict__ q, u16* __restrict__ k,
    u16* __restrict__ vt) {
  __shared__ u16 tile[32][33];
  if (blockIdx.y == 5) {
    const int bx = blockIdx.x;
    if (bx >= 2048) return;
    const int t0 = (bx & 63) * 32, d0 = ((bx >> 6) & 3) * 32;
    const int p = bx >> 8;              // b*NKV + kv
    const int b = p >> 2, kv = p & 3;
    const int tx = threadIdx.x & 31, ty = threadIdx.x >> 5;
#pragma unroll
    for (int i = 0; i < 4; ++i)
      tile[ty + 8 * i][tx] =
          qkv_lin[(size_t)(b * TT + t0 + ty + 8 * i) * NQKV + CC + NKV * HD + kv * HD + d0 + tx];
    __syncthreads();
    const int tperm = ((tx >> 2) & 3) * 8 + (tx & 3) + 4 * ((tx >> 4) & 1);
#pragma unroll
    for (int i = 0; i < 4; ++i)
      vt[((size_t)p * HD + d0 + ty + 8 * i) * TT + t0 + tperm] = tile[tx][ty + 8 * i];
    return;
  }
  const int bt = blockIdx.x;
  const int hh = blockIdx.y * 4 + (threadIdx.x >> 6);   // 0..19
  const int lane = threadIdx.x & 63;
  const int lam = lane & 31;
  const int t = bt & (TT - 1), b = bt >> 11;
  const int col = (hh < NH) ? hh * HD : CC + (hh - NH) * HD;
  const u16* src = qkv_lin + (size_t)bt * NQKV + col;
  const unsigned wv = *(const unsigned*)(src + 2 * lane);   // elems 2l, 2l+1
  const float e0 = bf2f((u16)(wv & 0xFFFFu)), e1 = bf2f((u16)(wv >> 16));
  float ss = e0 * e0 + e1 * e1;
#pragma unroll
  for (int mm = 1; mm < 64; mm <<= 1) ss += __shfl_xor(ss, mm, 64);
  const float rms = rsqrtf(ss * (1.f / 128.f) + 1.1920929e-7f);
  // gather RoPE pair for elements j = 2*lam, 2*lam+1
  const unsigned w1 = (unsigned)__shfl((int)wv, lam, 64);        // x1 pair
  const unsigned w2 = (unsigned)__shfl((int)wv, lam + 32, 64);   // x2 pair
  const float x1a = bf2f((u16)(w1 & 0xFFFFu)), x1b = bf2f((u16)(w1 >> 16));
  const float x2a = bf2f((u16)(w2 & 0xFFFFu)), x2b = bf2f((u16)(w2 >> 16));
  const float2 cs = *(const float2*)(cosp + t * HALF + 2 * lam);
  const float2 sn = *(const float2*)(sinp + t * HALF + 2 * lam);
  float oa, ob;
  if (lane < 32) {   // o1[j] = x1*rms*c - x2*rms*s
    oa = x1a * rms * cs.x - x2a * rms * sn.x;
    ob = x1b * rms * cs.y - x2b * rms * sn.y;
  } else {           // o2[j] = x1*rms*s + x2*rms*c
    oa = x1a * rms * sn.x + x2a * rms * cs.x;
    ob = x1b * rms * sn.y + x2b * rms * cs.y;
  }
  const unsigned ow = (unsigned)f2bf(oa) | ((unsigned)f2bf(ob) << 16);
  u16* dst = (hh < NH)
      ? q + (((size_t)(b * NH + hh)) * TT + t) * HD
      : k + (((size_t)(b * NKV + (hh - NH))) * TT + t) * HD;
  *(unsigned*)(dst + 2 * lane) = ow;   // elems 2l, 2l+1 (o1|o2 layout matches)
}

// ---------------------------------------------------------------------------
// S^T softmax + A-fragment pack, all in registers (v5-verified math).
// ---------------------------------------------------------------------------
__device__ __forceinline__ void softmax_pack(
    const f32x4* sacc, float& l_lane, bf16x8* ap, int rowq, int t0,
    bool diag, int quad) {
  const float cc = 0.12751744050808612f;   // log2(e)/sqrt(128)
  float e[4][4];
  if (diag) {
#pragma unroll
    for (int ct = 0; ct < 4; ++ct)
#pragma unroll
      for (int r = 0; r < 4; ++r) {
        float v = __builtin_amdgcn_exp2f(sacc[ct][r] * cc);
        if (t0 + ct * 16 + quad * 4 + r > rowq) v = 0.f;
        l_lane += v; e[ct][r] = v;
      }
  } else {
#pragma unroll
    for (int ct = 0; ct < 4; ++ct)
#pragma unroll
      for (int r = 0; r < 4; ++r) {
        float v = __builtin_amdgcn_exp2f(sacc[ct][r] * cc);
        l_lane += v; e[ct][r] = v;
      }
  }
#pragma unroll
  for (int k2 = 0; k2 < 2; ++k2) {
    bf16x8 ch;
#pragma unroll
    for (int j = 0; j < 8; ++j)
      ch[j] = (short)f2bf_hw(e[k2 * 2 + (j >> 2)][j & 3]);
    ap[k2] = ch;
  }
}

// ---------------------------------------------------------------------------
// MFMA flash attention v7 + XCD-LOCALITY SWIZZLE (r9). grid (16, 32) = 512
// blocks. Dispatched flat id fid -> xcd = fid&7, slot = fid>>3;
// bh = xcd*4 + slot/16, qt = slot&15 (bijective: 512 = 8x64). Under
// round-robin dispatch each XCD owns bh in {4x..4x+3} — and by GQA those 4
// heads share ONE kvh, so the per-XCD working set is K/V 1 MB + Q 2 MB
// < 4 MB L2. K/V reuse per L2 fill: 16 -> 64 blocks; kills the cross-XCD
// refetch of the same K/V panels (default round-robin spreads the 16
// qt-blocks of one bh over all 8 XCDs).
// ---------------------------------------------------------------------------
__global__ __launch_bounds__(512, 4) void attn_mfma(
    const u16* __restrict__ Qb, const u16* __restrict__ Kb,
    const u16* __restrict__ Vt, u16* __restrict__ Y) {
  __shared__ u16 Ks[2][8192];   // 16 sets (ct*4+kc) x 512, dbuf
  __shared__ u16 Vs[2][8192];   // 16 sets (dt*2+k2) x 512, dbuf

  const int fid = blockIdx.y * (int)gridDim.x + blockIdx.x;
  const int xcd = fid & 7, slot = fid >> 3;   // slot 0..63
  const int qt = slot & 15;                   // pair (qt, 31-qt)
  const int bh = xcd * 4 + (slot >> 4);       // 4 bh (1 kvh) per XCD
  const int b = bh >> 4, h = bh & 15, kvh = h >> 2;
  const int tid = threadIdx.x;
  const int wave = tid >> 6, lane = tid & 63;
  const int wg = wave >> 2, wv = wave & 3;   // wg: 0 = tile A, 1 = tile B
  const int quad = lane >> 4, lo = lane & 15;

  const int rows = (wg == 0) ? qt * 64 : (31 - qt) * 64;
  const u16* Qg = Qb + (size_t)(b * NH + h) * TT * HD;
  const u16* Kg = Kb + (size_t)(b * NKV + kvh) * TT * HD;
  const u16* Vg = Vt + (size_t)(b * NKV + kvh) * HD * TT;

  // Q fragments, used as MFMA B-operand (n=lo -> q-row, k=quad*8+j)
  bf16x8 aq[4];
#pragma unroll
  for (int kc = 0; kc < 4; ++kc)
    aq[kc] = *(const bf16x8*)(Qg + (size_t)(rows + wv * 16 + lo) * HD + kc * 32 + quad * 8);

  // staging: wave stages K sets {wave*2, wave*2+1} and V sets {wave*2, wave*2+1}
  const u16* kgp[2]; const u16* vgp[2];
  u16* klp[2][2]; u16* vlp[2][2];
#pragma unroll
  for (int c = 0; c < 2; ++c) {
    const int s = wave * 2 + c;          // 0..15
    const int ct = s >> 2, kq = s & 3;
    kgp[c] = Kg + (size_t)(ct * 16 + lo) * HD + kq * 32 + quad * 8;
    const int dt = s >> 1, k2 = s & 1;
    vgp[c] = Vg + (size_t)(dt * 16 + lo) * TT + k2 * 32 + quad * 8;
    klp[0][c] = &Ks[0][s * 512]; klp[1][c] = &Ks[1][s * 512];
    vlp[0][c] = &Vs[0][s * 512]; vlp[1][c] = &Vs[1][s * 512];
  }

  f32x4 oacc[8];
#pragma unroll
  for (int dt = 0; dt < 8; ++dt)
#pragma unroll
    for (int r = 0; r < 4; ++r) oacc[dt][r] = 0.f;
  float l_lane = 0.f;

  const int ntiles = 32 - qt;
  const int rowq = rows + wv * 16 + lo;   // this lane's q-row

  // prologue: stage tile 0 -> buf 0
#pragma unroll
  for (int c = 0; c < 2; ++c) {
    gl_lds16(kgp[c], klp[0][c]); kgp[c] += 64 * HD;
    gl_lds16(vgp[c], vlp[0][c]); vgp[c] += 64;
  }

  for (int nt = 0; nt < ntiles; ++nt) {
    const int par = nt & 1;
    __syncthreads();  // tile nt landed (vmcnt drained); buf[par^1] readers done
    if (nt + 1 < ntiles) {
#pragma unroll
      for (int c = 0; c < 2; ++c) {
        gl_lds16(kgp[c], klp[par ^ 1][c]); kgp[c] += 64 * HD;
        gl_lds16(vgp[c], vlp[par ^ 1][c]); vgp[c] += 64;
      }
    }
    const bool act = (wg == 1) || (nt <= qt);
    if (act) {
      const u16* ksb = Ks[par];
      const u16* vsb = Vs[par];
      const int t0 = nt * 64;

      // S^T = K Q^T: D row (quad*4+r) = kv, col (lo) = q-row
      f32x4 sacc[4];
#pragma unroll
      for (int ct = 0; ct < 4; ++ct)
#pragma unroll
        for (int r = 0; r < 4; ++r) sacc[ct][r] = 0.f;
      __builtin_amdgcn_s_setprio(1);
#pragma unroll
      for (int ct = 0; ct < 4; ++ct)
#pragma unroll
        for (int kc = 0; kc < 4; ++kc) {
          bf16x8 bk = *(const bf16x8*)&ksb[(ct * 4 + kc) * 512 + lane * 8];
          sacc[ct] = __builtin_amdgcn_mfma_f32_16x16x32_bf16(bk, aq[kc], sacc[ct], 0, 0, 0);
        }
      __builtin_amdgcn_s_setprio(0);

      // softmax + register P pack
      bf16x8 ap[2];
      softmax_pack(sacc, l_lane, ap, rowq, t0, t0 + 63 > rows + wv * 16, quad);

      // O += P @ V  (V already in permuted kv order matching the pack)
      __builtin_amdgcn_s_setprio(1);
#pragma unroll
      for (int dt = 0; dt < 8; ++dt)
#pragma unroll
        for (int k2 = 0; k2 < 2; ++k2) {
          bf16x8 bv = *(const bf16x8*)&vsb[(dt * 2 + k2) * 512 + lane * 8];
          oacc[dt] = __builtin_amdgcn_mfma_f32_16x16x32_bf16(ap[k2], bv, oacc[dt], 0, 0, 0);
        }
      __builtin_amdgcn_s_setprio(0);
    }
  }

  // epilogue: l for q-row `lo` -> reduce over quad lanes; fetch per-output-row
  float l = l_lane;
  l += __shfl_xor(l, 16, 64);
  l += __shfl_xor(l, 32, 64);
  l = 1.f / l;                       // valid at lane lo for row lo (all quads)
  float linv[4];
#pragma unroll
  for (int r = 0; r < 4; ++r)
    linv[r] = __shfl(l, quad * 4 + r, 64);   // row quad*4+r lives at lane quad*4+r
  const size_t row0 = (size_t)b * TT + rows + wv * 16 + quad * 4;
#pragma unroll
  for (int dt = 0; dt < 8; ++dt)
#pragma unroll
    for (int r = 0; r < 4; ++r)
      Y[(row0 + r) * CC + h * HD + dt * 16 + lo] = f2bf(oacc[dt][r] * linv[r]);
}

// ---------------------------------------------------------------------------
// kernel_launch. ws layout (bytes):
//   [0,16M):   xb (bf16 x)            -> later qb_buf (bf16 q, B,H,T,D)
//   [16M,28M): Wt (bf16 qkv^T)        -> later kb (4M) + vt (8M)
//   [28M,52M): qkv_lin bf16 (M x 3072)-> first 16M later y (bf16, M x C)
//   [52M,60M): Wot (bf16 Wo^T)
// ---------------------------------------------------------------------------
extern "C" void kernel_launch(void* const* d_in, const int* in_sizes, int n_in,
                              void* d_out, int out_size, void* d_ws, size_t ws_size,
                              hipStream_t stream) {
  (void)in_sizes; (void)n_in; (void)out_size; (void)ws_size;
  const float* x    = (const float*)d_in[0];
  const float* cosp = (const float*)d_in[1];
  const float* sinp = (const float*)d_in[2];
  const float* Wq   = (const float*)d_in[3];
  const float* Wk   = (const float*)d_in[4];
  const float* Wv   = (const float*)d_in[5];
  const float* Wo   = (const float*)d_in[6];
  const float* bo   = (const float*)d_in[7];
  float* out = (float*)d_out;
  char* ws = (char*)d_ws;

  const size_t MB = 1024 * 1024;
  u16* xb      = (u16*)(ws);
  u16* Wt      = (u16*)(ws + 16 * MB);
  u16* qkv_lin = (u16*)(ws + 28 * MB);
  u16* Wot     = (u16*)(ws + 52 * MB);
  u16* qb_buf  = (u16*)(ws);             // alias xb (dead after GEMM1)
  u16* kb      = (u16*)(ws + 16 * MB);   // alias Wt
  u16* vt      = (u16*)(ws + 20 * MB);   // alias Wt+4M
  u16* y       = (u16*)(ws + 28 * MB);   // alias qkv_lin head (dead after post)

  // 1. fused convert + weight transposes
  prep<<<dim3(64, 64, 5), dim3(32, 8), 0, stream>>>(x, Wq, Wk, Wv, Wo, xb, Wt, Wot);

  // 2. fused QKV GEMM (M=4096, N=3072, K=2048), bf16 out
  gemm_8ph<<<dim3(NQKV / 256, MTOT / 256), 512, 0, stream>>>(
      xb, Wt, nullptr, (float*)qkv_lin, MTOT, NQKV, CC, 1);

  // 3. fused RMSNorm+RoPE (y<5, vectorized) + V-transpose (y==5)
  qkv_post<<<dim3(MTOT, 6), 256, 0, stream>>>(qkv_lin, cosp, sinp, qb_buf, kb, vt);

  // 4. MFMA flash attention v7 + XCD-locality swizzle -> y bf16 (M x C)
  attn_mfma<<<dim3(16, BB * NH), 512, 0, stream>>>(qb_buf, kb, vt, y);

  // 5. out-proj GEMM + bias (fp32 out) — 256x128 tiles: 256 blocks = 1/CU
  gemm_n128<<<dim3(CC / 128, MTOT / 256), 512, 0, stream>>>(
      y, Wot, bo, out, MTOT, CC, CC, 0);
}

// Round 10
// 306.527 us; speedup vs baseline: 1.0113x; 1.0003x over previous
//
#include <hip/hip_runtime.h>
#include <hip/hip_bf16.h>
#include <math.h>

// Problem constants (B=2, T=2048, C=2048, NH=16, NKV=4, D=128, HALF=64)
#define BB 2
#define TT 2048
#define CC 2048
#define NH 16
#define NKV 4
#define HD 128
#define HALF 64
#define MTOT (BB*TT)            // 4096
#define NQKV (CC + 2*NKV*HD)    // 3072 (fused q|k|v columns)

typedef unsigned short u16;
typedef __attribute__((ext_vector_type(8))) short bf16x8;
typedef __attribute__((ext_vector_type(4))) float f32x4;

// fp32 -> bf16 (round-to-nearest-even), bit-twiddle form
__device__ __forceinline__ u16 f2bf(float f) {
  unsigned u = __float_as_uint(f);
  unsigned r = (u + 0x7FFFu + ((u >> 16) & 1u)) >> 16;
  return (u16)r;
}
// fp32 -> bf16 via HW convert (RNE, identical results; fewer VALU ops)
__device__ __forceinline__ u16 f2bf_hw(float f) {
  __hip_bfloat16 h = __float2bfloat16(f);
  return *reinterpret_cast<const u16*>(&h);
}
__device__ __forceinline__ float bf2f(u16 v) {
  return __uint_as_float(((unsigned)v) << 16);
}

// async global->LDS, 16B per lane; lds base must be wave-uniform (HW adds lane*16)
__device__ __forceinline__ void gl_lds16(const void* g, void* l) {
  __builtin_amdgcn_global_load_lds(
      (const __attribute__((address_space(1))) unsigned int*)g,
      (__attribute__((address_space(3))) unsigned int*)l, 16, 0, 0);
}

// XCD-chunked block swizzle (T1). Bijective iff nwg % 8 == 0
// (true for all grids here: 768, 512).
__device__ __forceinline__ int xcd_swz(int bid, int nwg) {
  return (bid & 7) * (nwg >> 3) + (bid >> 3);
}

// ---------------------------------------------------------------------------
// prep: fused x->bf16 convert (z=4) + 4 weight transposes (z=0..3).
// grid (64, 64, 5), block (32, 8).
// ---------------------------------------------------------------------------
__global__ __launch_bounds__(256) void prep(
    const float* __restrict__ x, const float* __restrict__ Wq,
    const float* __restrict__ Wk, const float* __restrict__ Wv,
    const float* __restrict__ Wo, u16* __restrict__ xb,
    u16* __restrict__ Wt, u16* __restrict__ Wot) {
  const int z = blockIdx.z;
  const int tx = threadIdx.x, ty = threadIdx.y;
  if (z == 4) {
    const int tid = ty * 32 + tx;
    const int i = (blockIdx.y * 64 + blockIdx.x) * 256 + tid;  // 8-elem group
    const float4* s4 = (const float4*)x;
    float4 a = s4[(size_t)i * 2], b = s4[(size_t)i * 2 + 1];
    bf16x8 o;
    o[0] = (short)f2bf(a.x); o[1] = (short)f2bf(a.y);
    o[2] = (short)f2bf(a.z); o[3] = (short)f2bf(a.w);
    o[4] = (short)f2bf(b.x); o[5] = (short)f2bf(b.y);
    o[6] = (short)f2bf(b.z); o[7] = (short)f2bf(b.w);
    ((bf16x8*)xb)[i] = o;
    return;
  }
  const float* W; u16* dst; int N; int row_off;
  if (z == 0)      { W = Wq; dst = Wt;  N = 2048; row_off = 0; }
  else if (z == 1) { W = Wk; dst = Wt;  N = 512;  row_off = 2048; }
  else if (z == 2) { W = Wv; dst = Wt;  N = 512;  row_off = 2560; }
  else             { W = Wo; dst = Wot; N = 2048; row_off = 0; }
  const int n0 = blockIdx.x * 32, k0 = blockIdx.y * 32;
  if (n0 >= N) return;
  __shared__ float tile[32][33];
#pragma unroll
  for (int i = 0; i < 4; ++i)
    tile[ty + 8 * i][tx] = W[(size_t)(k0 + ty + 8 * i) * N + n0 + tx];
  __syncthreads();
#pragma unroll
  for (int i = 0; i < 4; ++i)
    dst[(size_t)(row_off + n0 + ty + 8 * i) * CC + k0 + tx] =
        f2bf(tile[tx][ty + 8 * i]);
}

// ---------------------------------------------------------------------------
// 128x128 2-phase bf16 MFMA GEMM (r10) — dimension-halving of the r4-verified
// gemm_n128 template. 256 threads = 4 waves (2M x 2N); per-wave output 64x64
// (acc[4][4], identical to n128); BK=64. LDS 64 KB (A,B each 2 x 16 KB) ->
// **2 blocks/CU**: cross-block barrier desync (the r6-proven mechanism) plus
// perfect grid fill (QKV 768 = 3/CU exactly; out-proj 512 = 2/CU exactly),
// fixing gemm_8ph's 1-block/CU + 75%-fill and n128's 1-block/CU.
// Same both-sides row-XOR swizzle byte^=((row&7)<<4) (verified: conflicts ~0).
// Schedule per K-tile t (n128's, with load counts 4->6):
//   read all a(8)+b(8); stage A-h1(t+1)[2]; lgkm0; BARRIER;
//   MFMA cols01 (16); stage B-h0,B-h1,A-h0 (t+2)[6]  [all readers of buf pa
//   finished at the barrier -> overwrite legal]; vmcnt(6) [6 newest = t+2's
//   loads stay in flight => tile t+1 (A1 staged this iter pre-barrier, B/A0
//   staged last iter) fully landed]; MFMA cols23 (16); BARRIER.
// Prologue: tile0 (8) + tile1 B01/A0 (6); vmcnt(6) => tile0 landed.
// ---------------------------------------------------------------------------
__global__ __launch_bounds__(256, 2) void gemm_128(
    const u16* __restrict__ A, const u16* __restrict__ Bt,
    const float* __restrict__ bias, float* __restrict__ C,
    int M, int N, int K, int out_bf16) {
  __shared__ u16 As[16384];   // 2 x (128x64) bf16 = 2 x 16 KB
  __shared__ u16 Bs[16384];
  const int tid = threadIdx.x;
  const int w = tid >> 6, lane = tid & 63;      // w 0..3
  const int quad = lane >> 4, lo = lane & 15;
  const int wm = w >> 1, wn = w & 1;            // 2M x 2N wave grid
  const int nwg = gridDim.x * gridDim.y;
  const int swz = xcd_swz(blockIdx.y * gridDim.x + blockIdx.x, nwg);
  const int bm = (swz / gridDim.x) * 128, bn = (swz % gridDim.x) * 128;
  const int NT = K >> 6;                        // K-tiles of 64 (NT >= 3)

  // pre-swizzled staging sources: LDS byte X = h*8192 + (w*2+j)*1024 + lane*16
  // receives tile byte with col ^= ((row&7)<<4), row = X>>7 (128 B rows).
  const u16* agp[2][2]; const u16* bgp[2][2];
#pragma unroll
  for (int h = 0; h < 2; ++h)
#pragma unroll
    for (int j = 0; j < 2; ++j) {
      const unsigned X = (unsigned)h * 8192u +
                         (unsigned)((w * 2 + j) * 64 + lane) * 16u;
      const int row = (int)(X >> 7);
      const int ce = (int)(((X & 127u) ^ (((X >> 7) & 7u) << 4)) >> 1);
      agp[h][j] = A  + (size_t)(bm + row) * K + ce;
      bgp[h][j] = Bt + (size_t)(bn + row) * K + ce;
    }
  char* const lAs = (char*)As;
  char* const lBs = (char*)Bs;
  const int woff = w * 2048;

#define STGA8(hh, bufp, kt) do { \
    gl_lds16(agp[hh][0] + (size_t)(kt) * 64, lAs + (bufp) * 16384 + (hh) * 8192 + woff); \
    gl_lds16(agp[hh][1] + (size_t)(kt) * 64, lAs + (bufp) * 16384 + (hh) * 8192 + woff + 1024); \
  } while (0)
#define STGB8(hh, bufp, kt) do { \
    gl_lds16(bgp[hh][0] + (size_t)(kt) * 64, lBs + (bufp) * 16384 + (hh) * 8192 + woff); \
    gl_lds16(bgp[hh][1] + (size_t)(kt) * 64, lBs + (bufp) * 16384 + (hh) * 8192 + woff + 1024); \
  } while (0)

  const int sw  = (lo & 7) << 4;
  const int co0 = (quad * 16) ^ sw;
  const int co1 = (64 + quad * 16) ^ sw;
  const int aRB = (wm * 64 + lo) * 128;         // + i*2048
  const int bRB = (wn * 64 + lo) * 128;         // + ci*2048

  f32x4 acc[4][4];
#pragma unroll
  for (int i = 0; i < 4; ++i)
#pragma unroll
    for (int ci = 0; ci < 4; ++ci)
#pragma unroll
      for (int r = 0; r < 4; ++r) acc[i][ci][r] = 0.f;

  // prologue: tile0 full (8 loads) + tile1 B-h0,B-h1,A-h0 (6); keep 6 newest
  STGA8(0, 0, 0); STGA8(1, 0, 0); STGB8(0, 0, 0); STGB8(1, 0, 0);
  STGB8(0, 1, 1); STGB8(1, 1, 1); STGA8(0, 1, 1);
  asm volatile("s_waitcnt vmcnt(6)" ::: "memory");
  __builtin_amdgcn_s_barrier();

  for (int t = 0; t < NT; ++t) {
    const int pa = t & 1;
    const char* Ab = lAs + pa * 16384 + aRB;
    const char* Bb = lBs + pa * 16384 + bRB;
    bf16x8 a[4][2], b[4][2];
#pragma unroll
    for (int i = 0; i < 4; ++i) {
      a[i][0] = *(const bf16x8*)(Ab + i * 2048 + co0);
      a[i][1] = *(const bf16x8*)(Ab + i * 2048 + co1);
    }
#pragma unroll
    for (int ci = 0; ci < 4; ++ci) {
      b[ci][0] = *(const bf16x8*)(Bb + ci * 2048 + co0);
      b[ci][1] = *(const bf16x8*)(Bb + ci * 2048 + co1);
    }
    if (t + 1 < NT) STGA8(1, (t + 1) & 1, t + 1);
    asm volatile("s_waitcnt lgkmcnt(0)");   // own reads done BEFORE barrier
    __builtin_amdgcn_s_barrier();           // -> all waves' reads of buf pa done
    __builtin_amdgcn_s_setprio(1);
#pragma unroll
    for (int i = 0; i < 4; ++i)
#pragma unroll
      for (int ci = 0; ci < 2; ++ci) {
        acc[i][ci] = __builtin_amdgcn_mfma_f32_16x16x32_bf16(a[i][0], b[ci][0], acc[i][ci], 0, 0, 0);
        acc[i][ci] = __builtin_amdgcn_mfma_f32_16x16x32_bf16(a[i][1], b[ci][1], acc[i][ci], 0, 0, 0);
      }
    __builtin_amdgcn_s_setprio(0);
    if (t + 2 < NT) { STGB8(0, pa, t + 2); STGB8(1, pa, t + 2); STGA8(0, pa, t + 2); }
    if (t + 2 < NT)      asm volatile("s_waitcnt vmcnt(6)" ::: "memory");
    else if (t + 1 < NT) asm volatile("s_waitcnt vmcnt(0)" ::: "memory");
    __builtin_amdgcn_s_setprio(1);
#pragma unroll
    for (int i = 0; i < 4; ++i)
#pragma unroll
      for (int ci = 2; ci < 4; ++ci) {
        acc[i][ci] = __builtin_amdgcn_mfma_f32_16x16x32_bf16(a[i][0], b[ci][0], acc[i][ci], 0, 0, 0);
        acc[i][ci] = __builtin_amdgcn_mfma_f32_16x16x32_bf16(a[i][1], b[ci][1], acc[i][ci], 0, 0, 0);
      }
    __builtin_amdgcn_s_setprio(0);
    __builtin_amdgcn_s_barrier();           // next iter reads need all DMAs in
  }
#undef STGA8
#undef STGB8

  const int rbase = bm + wm * 64;
  const int cbase = bn + wn * 64;
#pragma unroll
  for (int i = 0; i < 4; ++i)
#pragma unroll
    for (int ci = 0; ci < 4; ++ci) {
      const int col = cbase + ci * 16 + lo;
      const float bv = bias ? bias[col] : 0.f;
#pragma unroll
      for (int r = 0; r < 4; ++r) {
        const int row = rbase + i * 16 + quad * 4 + r;
        const float v = acc[i][ci][r] + bv;
        if (out_bf16) ((u16*)C)[(size_t)row * N + col] = f2bf(v);
        else          C[(size_t)row * N + col] = v;
      }
    }
}

// ---------------------------------------------------------------------------
// FUSED qkv_post + v_transpose. grid (B*T, 6), block 256.
//   y in [0,5): RMSNorm + RoPE, vectorized u32 loads/stores (verified r8).
//   y == 5: v-transpose (verified r7).
// ---------------------------------------------------------------------------
__global__ __launch_bounds__(256) void qkv_post(
    const u16* __restrict__ qkv_lin, const float* __restrict__ cosp,
    const float* __restrict__ sinp, u16* __restrict__ q, u16* __restrict__ k,
    u16* __restrict__ vt) {
  __shared__ u16 tile[32][33];
  if (blockIdx.y == 5) {
    const int bx = blockIdx.x;
    if (bx >= 2048) return;
    const int t0 = (bx & 63) * 32, d0 = ((bx >> 6) & 3) * 32;
    const int p = bx >> 8;              // b*NKV + kv
    const int b = p >> 2, kv = p & 3;
    const int tx = threadIdx.x & 31, ty = threadIdx.x >> 5;
#pragma unroll
    for (int i = 0; i < 4; ++i)
      tile[ty + 8 * i][tx] =
          qkv_lin[(size_t)(b * TT + t0 + ty + 8 * i) * NQKV + CC + NKV * HD + kv * HD + d0 + tx];
    __syncthreads();
    const int tperm = ((tx >> 2) & 3) * 8 + (tx & 3) + 4 * ((tx >> 4) & 1);
#pragma unroll
    for (int i = 0; i < 4; ++i)
      vt[((size_t)p * HD + d0 + ty + 8 * i) * TT + t0 + tperm] = tile[tx][ty + 8 * i];
    return;
  }
  const int bt = blockIdx.x;
  const int hh = blockIdx.y * 4 + (threadIdx.x >> 6);   // 0..19
  const int lane = threadIdx.x & 63;
  const int lam = lane & 31;
  const int t = bt & (TT - 1), b = bt >> 11;
  const int col = (hh < NH) ? hh * HD : CC + (hh - NH) * HD;
  const u16* src = qkv_lin + (size_t)bt * NQKV + col;
  const unsigned wv = *(const unsigned*)(src + 2 * lane);   // elems 2l, 2l+1
  const float e0 = bf2f((u16)(wv & 0xFFFFu)), e1 = bf2f((u16)(wv >> 16));
  float ss = e0 * e0 + e1 * e1;
#pragma unroll
  for (int mm = 1; mm < 64; mm <<= 1) ss += __shfl_xor(ss, mm, 64);
  const float rms = rsqrtf(ss * (1.f / 128.f) + 1.1920929e-7f);
  // gather RoPE pair for elements j = 2*lam, 2*lam+1
  const unsigned w1 = (unsigned)__shfl((int)wv, lam, 64);        // x1 pair
  const unsigned w2 = (unsigned)__shfl((int)wv, lam + 32, 64);   // x2 pair
  const float x1a = bf2f((u16)(w1 & 0xFFFFu)), x1b = bf2f((u16)(w1 >> 16));
  const float x2a = bf2f((u16)(w2 & 0xFFFFu)), x2b = bf2f((u16)(w2 >> 16));
  const float2 cs = *(const float2*)(cosp + t * HALF + 2 * lam);
  const float2 sn = *(const float2*)(sinp + t * HALF + 2 * lam);
  float oa, ob;
  if (lane < 32) {   // o1[j] = x1*rms*c - x2*rms*s
    oa = x1a * rms * cs.x - x2a * rms * sn.x;
    ob = x1b * rms * cs.y - x2b * rms * sn.y;
  } else {           // o2[j] = x1*rms*s + x2*rms*c
    oa = x1a * rms * sn.x + x2a * rms * cs.x;
    ob = x1b * rms * sn.y + x2b * rms * cs.y;
  }
  const unsigned ow = (unsigned)f2bf(oa) | ((unsigned)f2bf(ob) << 16);
  u16* dst = (hh < NH)
      ? q + (((size_t)(b * NH + hh)) * TT + t) * HD
      : k + (((size_t)(b * NKV + (hh - NH))) * TT + t) * HD;
  *(unsigned*)(dst + 2 * lane) = ow;   // elems 2l, 2l+1 (o1|o2 layout matches)
}

// ---------------------------------------------------------------------------
// S^T softmax + A-fragment pack, all in registers (v5-verified math).
// ---------------------------------------------------------------------------
__device__ __forceinline__ void softmax_pack(
    const f32x4* sacc, float& l_lane, bf16x8* ap, int rowq, int t0,
    bool diag, int quad) {
  const float cc = 0.12751744050808612f;   // log2(e)/sqrt(128)
  float e[4][4];
  if (diag) {
#pragma unroll
    for (int ct = 0; ct < 4; ++ct)
#pragma unroll
      for (int r = 0; r < 4; ++r) {
        float v = __builtin_amdgcn_exp2f(sacc[ct][r] * cc);
        if (t0 + ct * 16 + quad * 4 + r > rowq) v = 0.f;
        l_lane += v; e[ct][r] = v;
      }
  } else {
#pragma unroll
    for (int ct = 0; ct < 4; ++ct)
#pragma unroll
      for (int r = 0; r < 4; ++r) {
        float v = __builtin_amdgcn_exp2f(sacc[ct][r] * cc);
        l_lane += v; e[ct][r] = v;
      }
  }
#pragma unroll
  for (int k2 = 0; k2 < 2; ++k2) {
    bf16x8 ch;
#pragma unroll
    for (int j = 0; j < 8; ++j)
      ch[j] = (short)f2bf_hw(e[k2 * 2 + (j >> 2)][j & 3]);
    ap[k2] = ch;
  }
}

// ---------------------------------------------------------------------------
// MFMA flash attention v7 + XCD-locality swizzle (r9-verified: FETCH 3x down,
// time-neutral; intra-block-serialization-bound — structurally plateaued).
// ---------------------------------------------------------------------------
__global__ __launch_bounds__(512, 4) void attn_mfma(
    const u16* __restrict__ Qb, const u16* __restrict__ Kb,
    const u16* __restrict__ Vt, u16* __restrict__ Y) {
  __shared__ u16 Ks[2][8192];   // 16 sets (ct*4+kc) x 512, dbuf
  __shared__ u16 Vs[2][8192];   // 16 sets (dt*2+k2) x 512, dbuf

  const int fid = blockIdx.y * (int)gridDim.x + blockIdx.x;
  const int xcd = fid & 7, slot = fid >> 3;   // slot 0..63
  const int qt = slot & 15;                   // pair (qt, 31-qt)
  const int bh = xcd * 4 + (slot >> 4);       // 4 bh (1 kvh) per XCD
  const int b = bh >> 4, h = bh & 15, kvh = h >> 2;
  const int tid = threadIdx.x;
  const int wave = tid >> 6, lane = tid & 63;
  const int wg = wave >> 2, wv = wave & 3;   // wg: 0 = tile A, 1 = tile B
  const int quad = lane >> 4, lo = lane & 15;

  const int rows = (wg == 0) ? qt * 64 : (31 - qt) * 64;
  const u16* Qg = Qb + (size_t)(b * NH + h) * TT * HD;
  const u16* Kg = Kb + (size_t)(b * NKV + kvh) * TT * HD;
  const u16* Vg = Vt + (size_t)(b * NKV + kvh) * HD * TT;

  // Q fragments, used as MFMA B-operand (n=lo -> q-row, k=quad*8+j)
  bf16x8 aq[4];
#pragma unroll
  for (int kc = 0; kc < 4; ++kc)
    aq[kc] = *(const bf16x8*)(Qg + (size_t)(rows + wv * 16 + lo) * HD + kc * 32 + quad * 8);

  // staging: wave stages K sets {wave*2, wave*2+1} and V sets {wave*2, wave*2+1}
  const u16* kgp[2]; const u16* vgp[2];
  u16* klp[2][2]; u16* vlp[2][2];
#pragma unroll
  for (int c = 0; c < 2; ++c) {
    const int s = wave * 2 + c;          // 0..15
    const int ct = s >> 2, kq = s & 3;
    kgp[c] = Kg + (size_t)(ct * 16 + lo) * HD + kq * 32 + quad * 8;
    const int dt = s >> 1, k2 = s & 1;
    vgp[c] = Vg + (size_t)(dt * 16 + lo) * TT + k2 * 32 + quad * 8;
    klp[0][c] = &Ks[0][s * 512]; klp[1][c] = &Ks[1][s * 512];
    vlp[0][c] = &Vs[0][s * 512]; vlp[1][c] = &Vs[1][s * 512];
  }

  f32x4 oacc[8];
#pragma unroll
  for (int dt = 0; dt < 8; ++dt)
#pragma unroll
    for (int r = 0; r < 4; ++r) oacc[dt][r] = 0.f;
  float l_lane = 0.f;

  const int ntiles = 32 - qt;
  const int rowq = rows + wv * 16 + lo;   // this lane's q-row

  // prologue: stage tile 0 -> buf 0
#pragma unroll
  for (int c = 0; c < 2; ++c) {
    gl_lds16(kgp[c], klp[0][c]); kgp[c] += 64 * HD;
    gl_lds16(vgp[c], vlp[0][c]); vgp[c] += 64;
  }

  for (int nt = 0; nt < ntiles; ++nt) {
    const int par = nt & 1;
    __syncthreads();  // tile nt landed (vmcnt drained); buf[par^1] readers done
    if (nt + 1 < ntiles) {
#pragma unroll
      for (int c = 0; c < 2; ++c) {
        gl_lds16(kgp[c], klp[par ^ 1][c]); kgp[c] += 64 * HD;
        gl_lds16(vgp[c], vlp[par ^ 1][c]); vgp[c] += 64;
      }
    }
    const bool act = (wg == 1) || (nt <= qt);
    if (act) {
      const u16* ksb = Ks[par];
      const u16* vsb = Vs[par];
      const int t0 = nt * 64;

      // S^T = K Q^T: D row (quad*4+r) = kv, col (lo) = q-row
      f32x4 sacc[4];
#pragma unroll
      for (int ct = 0; ct < 4; ++ct)
#pragma unroll
        for (int r = 0; r < 4; ++r) sacc[ct][r] = 0.f;
      __builtin_amdgcn_s_setprio(1);
#pragma unroll
      for (int ct = 0; ct < 4; ++ct)
#pragma unroll
        for (int kc = 0; kc < 4; ++kc) {
          bf16x8 bk = *(const bf16x8*)&ksb[(ct * 4 + kc) * 512 + lane * 8];
          sacc[ct] = __builtin_amdgcn_mfma_f32_16x16x32_bf16(bk, aq[kc], sacc[ct], 0, 0, 0);
        }
      __builtin_amdgcn_s_setprio(0);

      // softmax + register P pack
      bf16x8 ap[2];
      softmax_pack(sacc, l_lane, ap, rowq, t0, t0 + 63 > rows + wv * 16, quad);

      // O += P @ V  (V already in permuted kv order matching the pack)
      __builtin_amdgcn_s_setprio(1);
#pragma unroll
      for (int dt = 0; dt < 8; ++dt)
#pragma unroll
        for (int k2 = 0; k2 < 2; ++k2) {
          bf16x8 bv = *(const bf16x8*)&vsb[(dt * 2 + k2) * 512 + lane * 8];
          oacc[dt] = __builtin_amdgcn_mfma_f32_16x16x32_bf16(ap[k2], bv, oacc[dt], 0, 0, 0);
        }
      __builtin_amdgcn_s_setprio(0);
    }
  }

  // epilogue: l for q-row `lo` -> reduce over quad lanes; fetch per-output-row
  float l = l_lane;
  l += __shfl_xor(l, 16, 64);
  l += __shfl_xor(l, 32, 64);
  l = 1.f / l;                       // valid at lane lo for row lo (all quads)
  float linv[4];
#pragma unroll
  for (int r = 0; r < 4; ++r)
    linv[r] = __shfl(l, quad * 4 + r, 64);   // row quad*4+r lives at lane quad*4+r
  const size_t row0 = (size_t)b * TT + rows + wv * 16 + quad * 4;
#pragma unroll
  for (int dt = 0; dt < 8; ++dt)
#pragma unroll
    for (int r = 0; r < 4; ++r)
      Y[(row0 + r) * CC + h * HD + dt * 16 + lo] = f2bf(oacc[dt][r] * linv[r]);
}

// ---------------------------------------------------------------------------
// kernel_launch. ws layout (bytes):
//   [0,16M):   xb (bf16 x)            -> later qb_buf (bf16 q, B,H,T,D)
//   [16M,28M): Wt (bf16 qkv^T)        -> later kb (4M) + vt (8M)
//   [28M,52M): qkv_lin bf16 (M x 3072)-> first 16M later y (bf16, M x C)
//   [52M,60M): Wot (bf16 Wo^T)
// ---------------------------------------------------------------------------
extern "C" void kernel_launch(void* const* d_in, const int* in_sizes, int n_in,
                              void* d_out, int out_size, void* d_ws, size_t ws_size,
                              hipStream_t stream) {
  (void)in_sizes; (void)n_in; (void)out_size; (void)ws_size;
  const float* x    = (const float*)d_in[0];
  const float* cosp = (const float*)d_in[1];
  const float* sinp = (const float*)d_in[2];
  const float* Wq   = (const float*)d_in[3];
  const float* Wk   = (const float*)d_in[4];
  const float* Wv   = (const float*)d_in[5];
  const float* Wo   = (const float*)d_in[6];
  const float* bo   = (const float*)d_in[7];
  float* out = (float*)d_out;
  char* ws = (char*)d_ws;

  const size_t MB = 1024 * 1024;
  u16* xb      = (u16*)(ws);
  u16* Wt      = (u16*)(ws + 16 * MB);
  u16* qkv_lin = (u16*)(ws + 28 * MB);
  u16* Wot     = (u16*)(ws + 52 * MB);
  u16* qb_buf  = (u16*)(ws);             // alias xb (dead after GEMM1)
  u16* kb      = (u16*)(ws + 16 * MB);   // alias Wt
  u16* vt      = (u16*)(ws + 20 * MB);   // alias Wt+4M
  u16* y       = (u16*)(ws + 28 * MB);   // alias qkv_lin head (dead after post)

  // 1. fused convert + weight transposes
  prep<<<dim3(64, 64, 5), dim3(32, 8), 0, stream>>>(x, Wq, Wk, Wv, Wo, xb, Wt, Wot);

  // 2. fused QKV GEMM (M=4096, N=3072, K=2048), bf16 out
  //    128^2 tiles: 24x32 = 768 blocks = exactly 3/CU, 2 blocks/CU resident
  gemm_128<<<dim3(NQKV / 128, MTOT / 128), 256, 0, stream>>>(
      xb, Wt, nullptr, (float*)qkv_lin, MTOT, NQKV, CC, 1);

  // 3. fused RMSNorm+RoPE (y<5, vectorized) + V-transpose (y==5)
  qkv_post<<<dim3(MTOT, 6), 256, 0, stream>>>(qkv_lin, cosp, sinp, qb_buf, kb, vt);

  // 4. MFMA flash attention v7 + XCD-locality swizzle -> y bf16 (M x C)
  attn_mfma<<<dim3(16, BB * NH), 512, 0, stream>>>(qb_buf, kb, vt, y);

  // 5. out-proj GEMM + bias (fp32 out)
  //    128^2 tiles: 16x32 = 512 blocks = exactly 2/CU resident
  gemm_128<<<dim3(CC / 128, MTOT / 128), 256, 0, stream>>>(
      y, Wot, bo, out, MTOT, CC, CC, 0);
}

// Round 12
// 290.003 us; speedup vs baseline: 1.0689x; 1.0570x over previous
//
#include <hip/hip_runtime.h>
#include <hip/hip_bf16.h>
#include <math.h>

// Problem constants (B=2, T=2048, C=2048, NH=16, NKV=4, D=128, HALF=64)
#define BB 2
#define TT 2048
#define CC 2048
#define NH 16
#define NKV 4
#define HD 128
#define HALF 64
#define MTOT (BB*TT)            // 4096
#define NQKV (CC + 2*NKV*HD)    // 3072 (fused q|k|v columns)

typedef unsigned short u16;
typedef __attribute__((ext_vector_type(8))) short bf16x8;
typedef __attribute__((ext_vector_type(4))) float f32x4;

// fp32 -> bf16 (round-to-nearest-even), bit-twiddle form
__device__ __forceinline__ u16 f2bf(float f) {
  unsigned u = __float_as_uint(f);
  unsigned r = (u + 0x7FFFu + ((u >> 16) & 1u)) >> 16;
  return (u16)r;
}
// fp32 -> bf16 via HW convert (RNE, identical results; fewer VALU ops)
__device__ __forceinline__ u16 f2bf_hw(float f) {
  __hip_bfloat16 h = __float2bfloat16(f);
  return *reinterpret_cast<const u16*>(&h);
}
__device__ __forceinline__ float bf2f(u16 v) {
  return __uint_as_float(((unsigned)v) << 16);
}

// async global->LDS, 16B per lane; lds base must be wave-uniform (HW adds lane*16)
__device__ __forceinline__ void gl_lds16(const void* g, void* l) {
  __builtin_amdgcn_global_load_lds(
      (const __attribute__((address_space(1))) unsigned int*)g,
      (__attribute__((address_space(3))) unsigned int*)l, 16, 0, 0);
}

// XCD-chunked block swizzle (T1). Bijective iff nwg % 8 == 0
// (true for all grids here: 768, 512).
__device__ __forceinline__ int xcd_swz(int bid, int nwg) {
  return (bid & 7) * (nwg >> 3) + (bid >> 3);
}

// ---------------------------------------------------------------------------
// prep: fused x->bf16 convert (z=4) + 4 weight transposes (z=0..3).
// grid (64, 64, 5), block (32, 8).
// ---------------------------------------------------------------------------
__global__ __launch_bounds__(256) void prep(
    const float* __restrict__ x, const float* __restrict__ Wq,
    const float* __restrict__ Wk, const float* __restrict__ Wv,
    const float* __restrict__ Wo, u16* __restrict__ xb,
    u16* __restrict__ Wt, u16* __restrict__ Wot) {
  const int z = blockIdx.z;
  const int tx = threadIdx.x, ty = threadIdx.y;
  if (z == 4) {
    const int tid = ty * 32 + tx;
    const int i = (blockIdx.y * 64 + blockIdx.x) * 256 + tid;  // 8-elem group
    const float4* s4 = (const float4*)x;
    float4 a = s4[(size_t)i * 2], b = s4[(size_t)i * 2 + 1];
    bf16x8 o;
    o[0] = (short)f2bf(a.x); o[1] = (short)f2bf(a.y);
    o[2] = (short)f2bf(a.z); o[3] = (short)f2bf(a.w);
    o[4] = (short)f2bf(b.x); o[5] = (short)f2bf(b.y);
    o[6] = (short)f2bf(b.z); o[7] = (short)f2bf(b.w);
    ((bf16x8*)xb)[i] = o;
    return;
  }
  const float* W; u16* dst; int N; int row_off;
  if (z == 0)      { W = Wq; dst = Wt;  N = 2048; row_off = 0; }
  else if (z == 1) { W = Wk; dst = Wt;  N = 512;  row_off = 2048; }
  else if (z == 2) { W = Wv; dst = Wt;  N = 512;  row_off = 2560; }
  else             { W = Wo; dst = Wot; N = 2048; row_off = 0; }
  const int n0 = blockIdx.x * 32, k0 = blockIdx.y * 32;
  if (n0 >= N) return;
  __shared__ float tile[32][33];
#pragma unroll
  for (int i = 0; i < 4; ++i)
    tile[ty + 8 * i][tx] = W[(size_t)(k0 + ty + 8 * i) * N + n0 + tx];
  __syncthreads();
#pragma unroll
  for (int i = 0; i < 4; ++i)
    dst[(size_t)(row_off + n0 + ty + 8 * i) * CC + k0 + tx] =
        f2bf(tile[tx][ty + 8 * i]);
}

// ---------------------------------------------------------------------------
// 128x128 2-phase bf16 MFMA GEMM (r10-verified loop) with 4Mx1N wave grid
// + optional FUSED qkv epilogue (r11/r12).
// 256 threads = 4 waves; per-wave output 32 tokens x 128 dims: acc[2][8]
// (16 f32x4, same count as r10). Same LDS 64 KB double-buffer, same
// both-sides row-XOR swizzle (all reads keep row&7 == lo&7), same
// counted-vmcnt schedule: staging side byte-identical to r10.
// fuse=1 (QKV GEMM): each N-tile is exactly one head (NQKV = 24 x 128).
//   A wave holds full token rows -> RMSNorm: 8 reg squares + shfl_xor over
//   the 16-lane lo-group (the row's 128 dims live in lanes sharing quad);
//   RoPE pair = (acc[i][ci], acc[i][ci+4]) in-thread; q/k written head-major.
//   V-heads (tiles 20..23): LDS transpose (buffers dead post-loop) ->
//   kv-permuted vt writes. qkv_lin never materialized.
// fuse=0 (out-proj): plain C write in the 4Mx1N layout.
// ---------------------------------------------------------------------------
__global__ __launch_bounds__(256, 2) void gemm_128(
    const u16* __restrict__ A, const u16* __restrict__ Bt,
    const float* __restrict__ bias, float* __restrict__ C,
    int M, int N, int K, int out_bf16, int fuse,
    const float* __restrict__ cosp, const float* __restrict__ sinp,
    u16* __restrict__ qout, u16* __restrict__ kout, u16* __restrict__ vtout) {
  __shared__ u16 SH[32768];   // As = SH[0..16383], Bs = SH[16384..32767]
  const int tid = threadIdx.x;
  const int w = tid >> 6, lane = tid & 63;      // w 0..3
  const int quad = lane >> 4, lo = lane & 15;
  const int nwg = gridDim.x * gridDim.y;
  const int swz = xcd_swz(blockIdx.y * gridDim.x + blockIdx.x, nwg);
  const int bm = (swz / gridDim.x) * 128, bn = (swz % gridDim.x) * 128;
  const int NT = K >> 6;                        // K-tiles of 64 (NT >= 3)

  // pre-swizzled staging sources: LDS byte X = h*8192 + (w*2+j)*1024 + lane*16
  // receives tile byte with col ^= ((row&7)<<4), row = X>>7 (128 B rows).
  const u16* agp[2][2]; const u16* bgp[2][2];
#pragma unroll
  for (int h = 0; h < 2; ++h)
#pragma unroll
    for (int j = 0; j < 2; ++j) {
      const unsigned X = (unsigned)h * 8192u +
                         (unsigned)((w * 2 + j) * 64 + lane) * 16u;
      const int row = (int)(X >> 7);
      const int ce = (int)(((X & 127u) ^ (((X >> 7) & 7u) << 4)) >> 1);
      agp[h][j] = A  + (size_t)(bm + row) * K + ce;
      bgp[h][j] = Bt + (size_t)(bn + row) * K + ce;
    }
  char* const lAs = (char*)SH;
  char* const lBs = (char*)(SH + 16384);
  const int woff = w * 2048;

#define STGA8(hh, bufp, kt) do { \
    gl_lds16(agp[hh][0] + (size_t)(kt) * 64, lAs + (bufp) * 16384 + (hh) * 8192 + woff); \
    gl_lds16(agp[hh][1] + (size_t)(kt) * 64, lAs + (bufp) * 16384 + (hh) * 8192 + woff + 1024); \
  } while (0)
#define STGB8(hh, bufp, kt) do { \
    gl_lds16(bgp[hh][0] + (size_t)(kt) * 64, lBs + (bufp) * 16384 + (hh) * 8192 + woff); \
    gl_lds16(bgp[hh][1] + (size_t)(kt) * 64, lBs + (bufp) * 16384 + (hh) * 8192 + woff + 1024); \
  } while (0)

  const int sw  = (lo & 7) << 4;
  const int co0 = (quad * 16) ^ sw;
  const int co1 = (64 + quad * 16) ^ sw;
  const int aRB = (w * 32 + lo) * 128;          // + i*2048, i in 0..1
  const int bRB = lo * 128;                     // + ci*2048, ci in 0..7

  f32x4 acc[2][8];
#pragma unroll
  for (int i = 0; i < 2; ++i)
#pragma unroll
    for (int ci = 0; ci < 8; ++ci)
#pragma unroll
      for (int r = 0; r < 4; ++r) acc[i][ci][r] = 0.f;

  // prologue: tile0 full (8 loads) + tile1 B-h0,B-h1,A-h0 (6); keep 6 newest
  STGA8(0, 0, 0); STGA8(1, 0, 0); STGB8(0, 0, 0); STGB8(1, 0, 0);
  STGB8(0, 1, 1); STGB8(1, 1, 1); STGA8(0, 1, 1);
  asm volatile("s_waitcnt vmcnt(6)" ::: "memory");
  __builtin_amdgcn_s_barrier();

  for (int t = 0; t < NT; ++t) {
    const int pa = t & 1;
    const char* Ab = lAs + pa * 16384 + aRB;
    const char* Bb = lBs + pa * 16384 + bRB;
    bf16x8 a[2][2], b[8][2];
#pragma unroll
    for (int i = 0; i < 2; ++i) {
      a[i][0] = *(const bf16x8*)(Ab + i * 2048 + co0);
      a[i][1] = *(const bf16x8*)(Ab + i * 2048 + co1);
    }
#pragma unroll
    for (int ci = 0; ci < 8; ++ci) {
      b[ci][0] = *(const bf16x8*)(Bb + ci * 2048 + co0);
      b[ci][1] = *(const bf16x8*)(Bb + ci * 2048 + co1);
    }
    if (t + 1 < NT) STGA8(1, (t + 1) & 1, t + 1);
    asm volatile("s_waitcnt lgkmcnt(0)");   // own reads done BEFORE barrier
    __builtin_amdgcn_s_barrier();           // -> all waves' reads of buf pa done
    __builtin_amdgcn_s_setprio(1);
#pragma unroll
    for (int i = 0; i < 2; ++i)
#pragma unroll
      for (int ci = 0; ci < 4; ++ci) {
        acc[i][ci] = __builtin_amdgcn_mfma_f32_16x16x32_bf16(a[i][0], b[ci][0], acc[i][ci], 0, 0, 0);
        acc[i][ci] = __builtin_amdgcn_mfma_f32_16x16x32_bf16(a[i][1], b[ci][1], acc[i][ci], 0, 0, 0);
      }
    __builtin_amdgcn_s_setprio(0);
    if (t + 2 < NT) { STGB8(0, pa, t + 2); STGB8(1, pa, t + 2); STGA8(0, pa, t + 2); }
    if (t + 2 < NT)      asm volatile("s_waitcnt vmcnt(6)" ::: "memory");
    else if (t + 1 < NT) asm volatile("s_waitcnt vmcnt(0)" ::: "memory");
    __builtin_amdgcn_s_setprio(1);
#pragma unroll
    for (int i = 0; i < 2; ++i)
#pragma unroll
      for (int ci = 4; ci < 8; ++ci) {
        acc[i][ci] = __builtin_amdgcn_mfma_f32_16x16x32_bf16(a[i][0], b[ci][0], acc[i][ci], 0, 0, 0);
        acc[i][ci] = __builtin_amdgcn_mfma_f32_16x16x32_bf16(a[i][1], b[ci][1], acc[i][ci], 0, 0, 0);
      }
    __builtin_amdgcn_s_setprio(0);
    __builtin_amdgcn_s_barrier();           // next iter reads need all DMAs in
  }
#undef STGA8
#undef STGB8

  if (!fuse) {
    // plain write: row = bm + w*32 + i*16 + quad*4 + r, col = bn + ci*16 + lo
    const int rbase = bm + w * 32;
#pragma unroll
    for (int i = 0; i < 2; ++i)
#pragma unroll
      for (int ci = 0; ci < 8; ++ci) {
        const int col = bn + ci * 16 + lo;
        const float bv = bias ? bias[col] : 0.f;
#pragma unroll
        for (int r = 0; r < 4; ++r) {
          const int row = rbase + i * 16 + quad * 4 + r;
          const float v = acc[i][ci][r] + bv;
          if (out_bf16) ((u16*)C)[(size_t)row * N + col] = f2bf(v);
          else          C[(size_t)row * N + col] = v;
        }
      }
    return;
  }

  // -------- fused qkv epilogue (one head per N-tile) ----------------------
  const int htile = bn >> 7;   // 0..15 q | 16..19 k | 20..23 v
  if (htile < 20) {
#pragma unroll
    for (int i = 0; i < 2; ++i) {
      float ss[4];
#pragma unroll
      for (int r = 0; r < 4; ++r) {
        float s2 = 0.f;
#pragma unroll
        for (int ci = 0; ci < 8; ++ci) s2 += acc[i][ci][r] * acc[i][ci][r];
        ss[r] = s2;
      }
#pragma unroll
      for (int mm = 1; mm < 16; mm <<= 1)
#pragma unroll
        for (int r = 0; r < 4; ++r) ss[r] += __shfl_xor(ss[r], mm, 64);
#pragma unroll
      for (int r = 0; r < 4; ++r) {
        const float rmsv = rsqrtf(ss[r] * (1.f / 128.f) + 1.1920929e-7f);
        const int row = bm + w * 32 + i * 16 + quad * 4 + r;
        const int bb = row >> 11, tt = row & (TT - 1);
        u16* dst = (htile < NH)
            ? qout + (((size_t)(bb * NH + htile)) * TT + tt) * HD
            : kout + (((size_t)(bb * NKV + (htile - NH))) * TT + tt) * HD;
#pragma unroll
        for (int ci = 0; ci < 4; ++ci) {
          const int d = ci * 16 + lo;
          const float c = cosp[tt * HALF + d], s = sinp[tt * HALF + d];
          const float x1 = acc[i][ci][r] * rmsv;
          const float x2 = acc[i][ci + 4][r] * rmsv;
          dst[d]      = f2bf(x1 * c - x2 * s);
          dst[d + 64] = f2bf(x1 * s + x2 * c);
        }
      }
    }
  } else {
    // v-head: LDS transpose (SH free: all loop reads precede the final
    // barrier) then coalesced kv-permuted store to vt (B,KV,D,T).
    const int kv = htile - 20;
    __syncthreads();
#pragma unroll
    for (int i = 0; i < 2; ++i)
#pragma unroll
      for (int ci = 0; ci < 8; ++ci)
#pragma unroll
        for (int r = 0; r < 4; ++r)
          SH[(ci * 16 + lo) * 136 + w * 32 + i * 16 + quad * 4 + r] =
              f2bf(acc[i][ci][r]);
    __syncthreads();
    const int p = (bm >> 11) * NKV + kv;      // b*NKV + kv (tile within one b)
    const int t0g = bm & (TT - 1);
    const int tl = lane & 31;
    const int tp = ((tl >> 2) & 3) * 8 + (tl & 3) + 4 * ((tl >> 4) & 1);
#pragma unroll
    for (int dd = 0; dd < 32; ++dd) {
      const int d = w * 32 + dd;
#pragma unroll
      for (int tc = 0; tc < 2; ++tc) {
        const u16 v = SH[d * 136 + tc * 64 + lane];
        vtout[((size_t)p * HD + d) * TT + t0g + tc * 64 + (lane & 32) + tp] = v;
      }
    }
  }
}

// ---------------------------------------------------------------------------
// S^T softmax + A-fragment pack, all in registers (v5-verified math).
// ---------------------------------------------------------------------------
__device__ __forceinline__ void softmax_pack(
    const f32x4* sacc, float& l_lane, bf16x8* ap, int rowq, int t0,
    bool diag, int quad) {
  const float cc = 0.12751744050808612f;   // log2(e)/sqrt(128)
  float e[4][4];
  if (diag) {
#pragma unroll
    for (int ct = 0; ct < 4; ++ct)
#pragma unroll
      for (int r = 0; r < 4; ++r) {
        float v = __builtin_amdgcn_exp2f(sacc[ct][r] * cc);
        if (t0 + ct * 16 + quad * 4 + r > rowq) v = 0.f;
        l_lane += v; e[ct][r] = v;
      }
  } else {
#pragma unroll
    for (int ct = 0; ct < 4; ++ct)
#pragma unroll
      for (int r = 0; r < 4; ++r) {
        float v = __builtin_amdgcn_exp2f(sacc[ct][r] * cc);
        l_lane += v; e[ct][r] = v;
      }
  }
#pragma unroll
  for (int k2 = 0; k2 < 2; ++k2) {
    bf16x8 ch;
#pragma unroll
    for (int j = 0; j < 8; ++j)
      ch[j] = (short)f2bf_hw(e[k2 * 2 + (j >> 2)][j & 3]);
    ap[k2] = ch;
  }
}

// ---------------------------------------------------------------------------
// MFMA flash attention v7 + XCD-locality swizzle (r9-verified: FETCH 3x down,
// time-neutral; intra-block-serialization-bound — structurally plateaued).
// ---------------------------------------------------------------------------
__global__ __launch_bounds__(512, 4) void attn_mfma(
    const u16* __restrict__ Qb, const u16* __restrict__ Kb,
    const u16* __restrict__ Vt, u16* __restrict__ Y) {
  __shared__ u16 Ks[2][8192];   // 16 sets (ct*4+kc) x 512, dbuf
  __shared__ u16 Vs[2][8192];   // 16 sets (dt*2+k2) x 512, dbuf

  const int fid = blockIdx.y * (int)gridDim.x + blockIdx.x;
  const int xcd = fid & 7, slot = fid >> 3;   // slot 0..63
  const int qt = slot & 15;                   // pair (qt, 31-qt)
  const int bh = xcd * 4 + (slot >> 4);       // 4 bh (1 kvh) per XCD
  const int b = bh >> 4, h = bh & 15, kvh = h >> 2;
  const int tid = threadIdx.x;
  const int wave = tid >> 6, lane = tid & 63;
  const int wg = wave >> 2, wv = wave & 3;   // wg: 0 = tile A, 1 = tile B
  const int quad = lane >> 4, lo = lane & 15;

  const int rows = (wg == 0) ? qt * 64 : (31 - qt) * 64;
  const u16* Qg = Qb + (size_t)(b * NH + h) * TT * HD;
  const u16* Kg = Kb + (size_t)(b * NKV + kvh) * TT * HD;
  const u16* Vg = Vt + (size_t)(b * NKV + kvh) * HD * TT;

  // Q fragments, used as MFMA B-operand (n=lo -> q-row, k=quad*8+j)
  bf16x8 aq[4];
#pragma unroll
  for (int kc = 0; kc < 4; ++kc)
    aq[kc] = *(const bf16x8*)(Qg + (size_t)(rows + wv * 16 + lo) * HD + kc * 32 + quad * 8);

  // staging: wave stages K sets {wave*2, wave*2+1} and V sets {wave*2, wave*2+1}
  const u16* kgp[2]; const u16* vgp[2];
  u16* klp[2][2]; u16* vlp[2][2];
#pragma unroll
  for (int c = 0; c < 2; ++c) {
    const int s = wave * 2 + c;          // 0..15
    const int ct = s >> 2, kq = s & 3;
    kgp[c] = Kg + (size_t)(ct * 16 + lo) * HD + kq * 32 + quad * 8;
    const int dt = s >> 1, k2 = s & 1;
    vgp[c] = Vg + (size_t)(dt * 16 + lo) * TT + k2 * 32 + quad * 8;
    klp[0][c] = &Ks[0][s * 512]; klp[1][c] = &Ks[1][s * 512];
    vlp[0][c] = &Vs[0][s * 512]; vlp[1][c] = &Vs[1][s * 512];
  }

  f32x4 oacc[8];
#pragma unroll
  for (int dt = 0; dt < 8; ++dt)
#pragma unroll
    for (int r = 0; r < 4; ++r) oacc[dt][r] = 0.f;
  float l_lane = 0.f;

  const int ntiles = 32 - qt;
  const int rowq = rows + wv * 16 + lo;   // this lane's q-row

  // prologue: stage tile 0 -> buf 0
#pragma unroll
  for (int c = 0; c < 2; ++c) {
    gl_lds16(kgp[c], klp[0][c]); kgp[c] += 64 * HD;
    gl_lds16(vgp[c], vlp[0][c]); vgp[c] += 64;
  }

  for (int nt = 0; nt < ntiles; ++nt) {
    const int par = nt & 1;
    __syncthreads();  // tile nt landed (vmcnt drained); buf[par^1] readers done
    if (nt + 1 < ntiles) {
#pragma unroll
      for (int c = 0; c < 2; ++c) {
        gl_lds16(kgp[c], klp[par ^ 1][c]); kgp[c] += 64 * HD;
        gl_lds16(vgp[c], vlp[par ^ 1][c]); vgp[c] += 64;
      }
    }
    const bool act = (wg == 1) || (nt <= qt);
    if (act) {
      const u16* ksb = Ks[par];
      const u16* vsb = Vs[par];
      const int t0 = nt * 64;

      // S^T = K Q^T: D row (quad*4+r) = kv, col (lo) = q-row
      f32x4 sacc[4];
#pragma unroll
      for (int ct = 0; ct < 4; ++ct)
#pragma unroll
        for (int r = 0; r < 4; ++r) sacc[ct][r] = 0.f;
      __builtin_amdgcn_s_setprio(1);
#pragma unroll
      for (int ct = 0; ct < 4; ++ct)
#pragma unroll
        for (int kc = 0; kc < 4; ++kc) {
          bf16x8 bk = *(const bf16x8*)&ksb[(ct * 4 + kc) * 512 + lane * 8];
          sacc[ct] = __builtin_amdgcn_mfma_f32_16x16x32_bf16(bk, aq[kc], sacc[ct], 0, 0, 0);
        }
      __builtin_amdgcn_s_setprio(0);

      // softmax + register P pack
      bf16x8 ap[2];
      softmax_pack(sacc, l_lane, ap, rowq, t0, t0 + 63 > rows + wv * 16, quad);

      // O += P @ V  (V already in permuted kv order matching the pack)
      __builtin_amdgcn_s_setprio(1);
#pragma unroll
      for (int dt = 0; dt < 8; ++dt)
#pragma unroll
        for (int k2 = 0; k2 < 2; ++k2) {
          bf16x8 bv = *(const bf16x8*)&vsb[(dt * 2 + k2) * 512 + lane * 8];
          oacc[dt] = __builtin_amdgcn_mfma_f32_16x16x32_bf16(ap[k2], bv, oacc[dt], 0, 0, 0);
        }
      __builtin_amdgcn_s_setprio(0);
    }
  }

  // epilogue: l for q-row `lo` -> reduce over quad lanes; fetch per-output-row
  float l = l_lane;
  l += __shfl_xor(l, 16, 64);
  l += __shfl_xor(l, 32, 64);
  l = 1.f / l;                       // valid at lane lo for row lo (all quads)
  float linv[4];
#pragma unroll
  for (int r = 0; r < 4; ++r)
    linv[r] = __shfl(l, quad * 4 + r, 64);   // row quad*4+r lives at lane quad*4+r
  const size_t row0 = (size_t)b * TT + rows + wv * 16 + quad * 4;
#pragma unroll
  for (int dt = 0; dt < 8; ++dt)
#pragma unroll
    for (int r = 0; r < 4; ++r)
      Y[(row0 + r) * CC + h * HD + dt * 16 + lo] = f2bf(oacc[dt][r] * linv[r]);
}

// ---------------------------------------------------------------------------
// kernel_launch. ws layout (disjoint per stage):
//   xb  [0,16M)    bf16 x             (written by prep; read by GEMM1; dead after)
//   Wt  [16M,28M)  bf16 qkv^T         (prep -> GEMM1)
//   kb  [28M,32M)  bf16 k (B,KV,T,D)  (GEMM1 -> attn)
//   vt  [32M,36M)  bf16 v (B,KV,D,T)  (GEMM1 -> attn)
//   qb  [36M,52M)  bf16 q (B,H,T,D)   (GEMM1 -> attn)
//   y   [0,16M)    bf16 attn out      (aliases xb, which is dead by then)
//   Wot [52M,60M)  bf16 Wo^T          (prep -> out-proj)
// Pipeline (r12): prep -> gemm_128(QKV, fused rms/rope/vtrans epilogue)
//   -> attn -> gemm_128(out-proj). qkv_lin round-trip eliminated.
// ---------------------------------------------------------------------------
extern "C" void kernel_launch(void* const* d_in, const int* in_sizes, int n_in,
                              void* d_out, int out_size, void* d_ws, size_t ws_size,
                              hipStream_t stream) {
  (void)in_sizes; (void)n_in; (void)out_size; (void)ws_size;
  const float* x    = (const float*)d_in[0];
  const float* cosp = (const float*)d_in[1];
  const float* sinp = (const float*)d_in[2];
  const float* Wq   = (const float*)d_in[3];
  const float* Wk   = (const float*)d_in[4];
  const float* Wv   = (const float*)d_in[5];
  const float* Wo   = (const float*)d_in[6];
  const float* bo   = (const float*)d_in[7];
  float* out = (float*)d_out;
  char* ws = (char*)d_ws;

  const size_t MB = 1024 * 1024;
  u16* xb     = (u16*)(ws);
  u16* Wt     = (u16*)(ws + 16 * MB);
  u16* kb     = (u16*)(ws + 28 * MB);
  u16* vt     = (u16*)(ws + 32 * MB);
  u16* qb_buf = (u16*)(ws + 36 * MB);
  u16* Wot    = (u16*)(ws + 52 * MB);
  u16* y      = (u16*)(ws);              // alias xb (dead after GEMM1)

  // 1. fused convert + weight transposes
  prep<<<dim3(64, 64, 5), dim3(32, 8), 0, stream>>>(x, Wq, Wk, Wv, Wo, xb, Wt, Wot);

  // 2. fused QKV GEMM (M=4096, N=3072, K=2048) + RMSNorm/RoPE/V-transpose
  //    epilogue. 24x32 = 768 blocks = exactly 3/CU, 2 blocks/CU resident.
  gemm_128<<<dim3(NQKV / 128, MTOT / 128), 256, 0, stream>>>(
      xb, Wt, nullptr, nullptr, MTOT, NQKV, CC, 1, 1,
      cosp, sinp, qb_buf, kb, vt);

  // 3. MFMA flash attention v7 + XCD-locality swizzle -> y bf16 (M x C)
  attn_mfma<<<dim3(16, BB * NH), 512, 0, stream>>>(qb_buf, kb, vt, y);

  // 4. out-proj GEMM + bias (fp32 out). 16x32 = 512 blocks = 2/CU.
  gemm_128<<<dim3(CC / 128, MTOT / 128), 256, 0, stream>>>(
      y, Wot, bo, out, MTOT, CC, CC, 0, 0,
      nullptr, nullptr, nullptr, nullptr, nullptr);
}